// Round 1
// baseline (1205.382 us; speedup 1.0000x reference)
//
#include <hip/hip_runtime.h>
#include <hip/hip_bf16.h>

#define BATCH 2
#define SEQ 2048
#define DMODEL 1024
#define NH 16
#define HD 64
#define NRF 266
#define CHK 128
#define NCH 16
#define NBH 32
#define NROWS 4096  // BATCH*SEQ

constexpr float SCAL = 0.17677669529663687f;   // DMODEL^-0.25
constexpr float SCAL2 = 0.03125f;              // SCAL^2 = DMODEL^-0.5
constexpr float CNORM = 0.06131393094576169f;  // 1/sqrt(NRF)
constexpr float KEPS = 1e-4f;

// ---------------- GEMM: C[4096x1024] = A[4096x1024] @ W[1024x1024] + bias ----------------
__global__ __launch_bounds__(256) void gemm_bias_f32(
    const float* __restrict__ A, const float* __restrict__ W,
    const float* __restrict__ bias, float* __restrict__ C) {
  __shared__ float As[16][68];  // [k][m]
  __shared__ float Bs[16][68];  // [k][n]
  int tid = threadIdx.x;
  int bm = blockIdx.y << 6, bn = blockIdx.x << 6;
  int ty = tid >> 4, tx = tid & 15;
  int lm = tid >> 2, lk = (tid & 3) << 2;
  int lk2 = tid >> 4, ln = (tid & 15) << 2;
  float acc[4][4] = {};
  for (int k0 = 0; k0 < DMODEL; k0 += 16) {
    float4 av = *(const float4*)&A[(size_t)(bm + lm) * DMODEL + k0 + lk];
    float4 bv = *(const float4*)&W[(size_t)(k0 + lk2) * DMODEL + bn + ln];
    As[lk + 0][lm] = av.x;
    As[lk + 1][lm] = av.y;
    As[lk + 2][lm] = av.z;
    As[lk + 3][lm] = av.w;
    *(float4*)&Bs[lk2][ln] = bv;
    __syncthreads();
#pragma unroll
    for (int k = 0; k < 16; ++k) {
      float4 a = *(const float4*)&As[k][ty << 2];
      float4 b = *(const float4*)&Bs[k][tx << 2];
      acc[0][0] += a.x * b.x; acc[0][1] += a.x * b.y; acc[0][2] += a.x * b.z; acc[0][3] += a.x * b.w;
      acc[1][0] += a.y * b.x; acc[1][1] += a.y * b.y; acc[1][2] += a.y * b.z; acc[1][3] += a.y * b.w;
      acc[2][0] += a.z * b.x; acc[2][1] += a.z * b.y; acc[2][2] += a.z * b.z; acc[2][3] += a.z * b.w;
      acc[3][0] += a.w * b.x; acc[3][1] += a.w * b.y; acc[3][2] += a.w * b.z; acc[3][3] += a.w * b.w;
    }
    __syncthreads();
  }
  float4 bb = *(const float4*)&bias[bn + (tx << 2)];
#pragma unroll
  for (int i = 0; i < 4; ++i) {
    int row = bm + (ty << 2) + i;
    float4 o = make_float4(acc[i][0] + bb.x, acc[i][1] + bb.y,
                           acc[i][2] + bb.z, acc[i][3] + bb.w);
    *(float4*)&C[(size_t)row * DMODEL + bn + (tx << 2)] = o;
  }
}

// ---------------- h_k per (b,h,l) + per-block max ----------------
__global__ __launch_bounds__(256) void hk_kernel(const float* __restrict__ Kproj,
                                                 float* __restrict__ hkbuf,
                                                 float* __restrict__ pmax) {
  int n = blockIdx.x;  // b*SEQ + l
  int tid = threadIdx.x;
  float4 kv = *(const float4*)&Kproj[(size_t)n * DMODEL + (tid << 2)];
  float ss = kv.x * kv.x + kv.y * kv.y + kv.z * kv.z + kv.w * kv.w;
#pragma unroll
  for (int off = 8; off >= 1; off >>= 1) ss += __shfl_xor(ss, off, 16);
  float hkv = -0.5f * SCAL2 * ss;
  int h = tid >> 4;
  if ((tid & 15) == 0) {
    int b = n >> 11, l = n & (SEQ - 1);
    hkbuf[((size_t)(b * NH + h)) * SEQ + l] = hkv;
  }
  __shared__ float red[256];
  red[tid] = hkv;
  __syncthreads();
  for (int s = 128; s > 0; s >>= 1) {
    if (tid < s) red[tid] = fmaxf(red[tid], red[tid + s]);
    __syncthreads();
  }
  if (tid == 0) pmax[n] = red[0];
}

__global__ __launch_bounds__(256) void maxreduce_kernel(const float* __restrict__ pmax,
                                                        float* __restrict__ kstab) {
  int tid = threadIdx.x;
  float m = -3.0e38f;
  for (int i = tid; i < NROWS; i += 256) m = fmaxf(m, pmax[i]);
  __shared__ float red[256];
  red[tid] = m;
  __syncthreads();
  for (int s = 128; s > 0; s >>= 1) {
    if (tid < s) red[tid] = fmaxf(red[tid], red[tid + s]);
    __syncthreads();
  }
  if (tid == 0) *kstab = red[0];
}

// ---------------- feature map: Q' = c*(exp(q@rf^T)+eps), K' = c*(exp(hk + k@rf^T - kstab)+eps)
__global__ __launch_bounds__(256) void featmap_kernel(
    const float* __restrict__ Qproj, const float* __restrict__ Kproj,
    const float* __restrict__ rf, const float* __restrict__ hkbuf,
    const float* __restrict__ kstab,
    __hip_bfloat16* __restrict__ Qp, __hip_bfloat16* __restrict__ Kp) {
  __shared__ float rfs[NRF][65];
  __shared__ float qsh[32][65];
  int isK = blockIdx.z;
  const float* X = isK ? Kproj : Qproj;
  __hip_bfloat16* O = isK ? Kp : Qp;
  int bh = blockIdx.y, b = bh >> 4, h = bh & 15;
  int l0 = blockIdx.x << 5;
  int tid = threadIdx.x;
  for (int idx = tid; idx < NRF * HD; idx += 256)
    rfs[idx >> 6][idx & 63] = rf[idx];
  for (int idx = tid; idx < 32 * HD; idx += 256) {
    int r = idx >> 6, d = idx & 63;
    qsh[r][d] = X[((size_t)b * SEQ + l0 + r) * DMODEL + h * HD + d] * SCAL;
  }
  __syncthreads();
  int rg = tid >> 6, mg = tid & 63;  // thread owns rows {rg,rg+4,..,rg+28}, m in {mg,mg+64,..}
  float acc[8][5];
#pragma unroll
  for (int i = 0; i < 8; ++i)
#pragma unroll
    for (int j = 0; j < 5; ++j) acc[i][j] = 0.f;
  for (int d = 0; d < HD; ++d) {
    float qv[8];
#pragma unroll
    for (int rr = 0; rr < 8; ++rr) qv[rr] = qsh[rg + (rr << 2)][d];
    float rv[5];
#pragma unroll
    for (int jm = 0; jm < 4; ++jm) rv[jm] = rfs[mg + (jm << 6)][d];
    rv[4] = (mg < 10) ? rfs[mg + 256][d] : 0.f;
#pragma unroll
    for (int rr = 0; rr < 8; ++rr)
#pragma unroll
      for (int jm = 0; jm < 5; ++jm) acc[rr][jm] += qv[rr] * rv[jm];
  }
  float ksv = isK ? *kstab : 0.f;
#pragma unroll
  for (int rr = 0; rr < 8; ++rr) {
    int l = l0 + rg + (rr << 2);
    float addk = isK ? (hkbuf[(size_t)bh * SEQ + l] - ksv) : 0.f;
    size_t rowb = ((size_t)bh * SEQ + l) * NRF;
#pragma unroll
    for (int jm = 0; jm < 5; ++jm) {
      int m = mg + (jm << 6);
      if (m < NRF)
        O[rowb + m] = __float2bfloat16(CNORM * (expf(acc[rr][jm] + addk) + KEPS));
    }
  }
}

// ---------------- per-chunk sums: Ssum[m][d] = sum_i k'_i[m] v_i[d]; ksum[m] = sum_i k'_i[m]
__global__ __launch_bounds__(256) void chunksum_kernel(
    const __hip_bfloat16* __restrict__ Kp, const float* __restrict__ V,
    float* __restrict__ Ssum, float* __restrict__ ksum) {
  int c = blockIdx.x, bh = blockIdx.y;
  int b = bh >> 4, h = bh & 15;
  __shared__ float ksh[32][NRF];
  __shared__ float vsh[32][HD];
  int tid = threadIdx.x;
  int mg = tid >> 4, dg = tid & 15;  // m in {mg,mg+16,...}, d = dg*4..+3
  float acc[17][4];
#pragma unroll
  for (int jm = 0; jm < 17; ++jm)
#pragma unroll
    for (int jd = 0; jd < 4; ++jd) acc[jm][jd] = 0.f;
  float kacc[17];
#pragma unroll
  for (int jm = 0; jm < 17; ++jm) kacc[jm] = 0.f;
  for (int it = 0; it < 4; ++it) {
    __syncthreads();
    int i0 = c * CHK + (it << 5);
    for (int idx = tid; idx < 32 * NRF; idx += 256) {
      int i = idx / NRF, m = idx - i * NRF;
      ksh[i][m] = __bfloat162float(Kp[((size_t)bh * SEQ + i0 + i) * NRF + m]);
    }
    for (int idx = tid; idx < 32 * HD; idx += 256) {
      int i = idx >> 6, d = idx & 63;
      vsh[i][d] = V[((size_t)b * SEQ + i0 + i) * DMODEL + h * HD + d];
    }
    __syncthreads();
    for (int i = 0; i < 32; ++i) {
      float4 v4 = *(const float4*)&vsh[i][dg << 2];
#pragma unroll
      for (int jm = 0; jm < 16; ++jm) {
        float kv = ksh[i][mg + (jm << 4)];
        acc[jm][0] += kv * v4.x; acc[jm][1] += kv * v4.y;
        acc[jm][2] += kv * v4.z; acc[jm][3] += kv * v4.w;
      }
      if (mg < 10) {
        float kv = ksh[i][mg + 256];
        acc[16][0] += kv * v4.x; acc[16][1] += kv * v4.y;
        acc[16][2] += kv * v4.z; acc[16][3] += kv * v4.w;
      }
      if (dg == 0) {
#pragma unroll
        for (int jm = 0; jm < 16; ++jm) kacc[jm] += ksh[i][mg + (jm << 4)];
        if (mg < 10) kacc[16] += ksh[i][mg + 256];
      }
    }
  }
  size_t sbase = ((size_t)bh * NCH + c) * (size_t)(NRF * HD);
  size_t kbase = ((size_t)bh * NCH + c) * (size_t)NRF;
#pragma unroll
  for (int jm = 0; jm < 16; ++jm) {
    int m = mg + (jm << 4);
    *(float4*)&Ssum[sbase + (size_t)m * HD + (dg << 2)] =
        make_float4(acc[jm][0], acc[jm][1], acc[jm][2], acc[jm][3]);
    if (dg == 0) ksum[kbase + m] = kacc[jm];
  }
  if (mg < 10) {
    int m = mg + 256;
    *(float4*)&Ssum[sbase + (size_t)m * HD + (dg << 2)] =
        make_float4(acc[16][0], acc[16][1], acc[16][2], acc[16][3]);
    if (dg == 0) ksum[kbase + m] = kacc[16];
  }
}

// ---------------- exclusive prefix over chunks (in place) ----------------
__global__ void prefix_S_kernel(float* __restrict__ Ssum) {
  int tid = blockIdx.x * 256 + threadIdx.x;
  if (tid >= NBH * NRF * HD) return;
  int bh = tid / (NRF * HD);
  int e = tid - bh * (NRF * HD);
  size_t base = (size_t)bh * NCH * (NRF * HD) + e;
  float a = 0.f;
#pragma unroll
  for (int c = 0; c < NCH; ++c) {
    size_t idx = base + (size_t)c * (NRF * HD);
    float v = Ssum[idx];
    Ssum[idx] = a;
    a += v;
  }
}

__global__ void prefix_k_kernel(float* __restrict__ ksum) {
  int tid = blockIdx.x * 256 + threadIdx.x;
  if (tid >= NBH * NRF) return;
  int bh = tid / NRF;
  int m = tid - bh * NRF;
  size_t base = (size_t)bh * NCH * NRF + m;
  float a = 0.f;
#pragma unroll
  for (int c = 0; c < NCH; ++c) {
    size_t idx = base + (size_t)c * NRF;
    float v = ksum[idx];
    ksum[idx] = a;
    a += v;
  }
}

// ---------------- inter-chunk: numA = Q' @ S_prev ; denA = Q' @ ksum_prev ----------------
__global__ __launch_bounds__(256) void inter_kernel(
    const __hip_bfloat16* __restrict__ Qp, const float* __restrict__ Sprev,
    const float* __restrict__ ksprev, float* __restrict__ numA,
    float* __restrict__ denA) {
  int c = blockIdx.x, bh = blockIdx.y;
  __shared__ float Ssh[NRF * HD];
  __shared__ float kssh[NRF];
  __shared__ float qsh[4][NRF];
  int tid = threadIdx.x;
  size_t sbase = ((size_t)bh * NCH + c) * (size_t)(NRF * HD);
  for (int idx = tid; idx < NRF * HD; idx += 256) Ssh[idx] = Sprev[sbase + idx];
  for (int idx = tid; idx < NRF; idx += 256)
    kssh[idx] = ksprev[((size_t)bh * NCH + c) * (size_t)NRF + idx];
  int d = tid & 63, ig = tid >> 6;
  size_t rowb = (size_t)bh * SEQ + (size_t)c * CHK;
  for (int ii = 0; ii < 32; ++ii) {
    __syncthreads();
    for (int idx = tid; idx < 4 * NRF; idx += 256) {
      int jg = idx / NRF, m = idx - jg * NRF;
      qsh[jg][m] = __bfloat162float(Qp[(rowb + (ii << 2) + jg) * NRF + m]);
    }
    __syncthreads();
    float a = 0.f;
#pragma unroll 2
    for (int m = 0; m < NRF; ++m) a += qsh[ig][m] * Ssh[m * HD + d];
    numA[(rowb + (ii << 2) + ig) * HD + d] = a;
  }
  __syncthreads();
  if (tid < CHK) {
    const __hip_bfloat16* qr = Qp + (rowb + tid) * NRF;
    float a = 0.f;
#pragma unroll 2
    for (int m = 0; m < NRF; ++m) a += __bfloat162float(qr[m]) * kssh[m];
    denA[rowb + tid] = a;
  }
}

// ---------------- intra-chunk: masked (Q'K'^T) @ V, rowsum; finalize ctx ----------------
__global__ __launch_bounds__(256) void intra_kernel(
    const __hip_bfloat16* __restrict__ Qp, const __hip_bfloat16* __restrict__ Kp,
    const float* __restrict__ V, const float* __restrict__ numA,
    const float* __restrict__ denA, float* __restrict__ ctx) {
  int c = blockIdx.x, bh = blockIdx.y;
  int b = bh >> 4, h = bh & 15;
  __shared__ float qsh[32][NRF];
  __shared__ float ksh[32][NRF];
  __shared__ float vsh[32][HD];
  __shared__ float Psh[32][33];
  int tid = threadIdx.x;
  int il = tid >> 3;  // PV: i_loc
  int dg = tid & 7;   // PV: d-group (8 d's)
  int iq = tid >> 4, jp = tid & 15;  // P: 2x2 per thread
  size_t rowb = (size_t)bh * SEQ + (size_t)c * CHK;
  for (int it = 0; it < 4; ++it) {
    __syncthreads();
    for (int idx = tid; idx < 32 * NRF; idx += 256) {
      int i = idx / NRF, m = idx - i * NRF;
      qsh[i][m] = __bfloat162float(Qp[(rowb + (it << 5) + i) * NRF + m]);
    }
    __syncthreads();
    float acc[8];
#pragma unroll
    for (int jd = 0; jd < 8; ++jd) acc[jd] = 0.f;
    float den = 0.f;
    for (int jt = 0; jt <= it; ++jt) {
      __syncthreads();
      for (int idx = tid; idx < 32 * NRF; idx += 256) {
        int j = idx / NRF, m = idx - j * NRF;
        ksh[j][m] = __bfloat162float(Kp[(rowb + (jt << 5) + j) * NRF + m]);
      }
      for (int idx = tid; idx < 32 * HD; idx += 256) {
        int j = idx >> 6, dd = idx & 63;
        vsh[j][dd] =
            V[((size_t)b * SEQ + (size_t)c * CHK + (jt << 5) + j) * DMODEL + h * HD + dd];
      }
      __syncthreads();
      int i0 = iq << 1, j0 = jp << 1;
      float p00 = 0.f, p01 = 0.f, p10 = 0.f, p11 = 0.f;
#pragma unroll 2
      for (int m = 0; m < NRF; ++m) {
        float q0 = qsh[i0][m], q1 = qsh[i0 + 1][m];
        float k0 = ksh[j0][m], k1 = ksh[j0 + 1][m];
        p00 += q0 * k0; p01 += q0 * k1;
        p10 += q1 * k0; p11 += q1 * k1;
      }
      if (jt == it) {  // causal mask within diagonal tile
        if (j0 > i0) p00 = 0.f;
        if (j0 + 1 > i0) p01 = 0.f;
        if (j0 > i0 + 1) p10 = 0.f;
        if (j0 + 1 > i0 + 1) p11 = 0.f;
      }
      Psh[i0][j0] = p00;
      Psh[i0][j0 + 1] = p01;
      Psh[i0 + 1][j0] = p10;
      Psh[i0 + 1][j0 + 1] = p11;
      __syncthreads();
#pragma unroll 4
      for (int j = 0; j < 32; ++j) {
        float p = Psh[il][j];
        den += p;
        const float* vr = &vsh[j][dg << 3];
#pragma unroll
        for (int jd = 0; jd < 8; ++jd) acc[jd] += p * vr[jd];
      }
    }
    size_t grow = rowb + (it << 5) + il;
    float dtot = denA[grow] + den;
    float inv = 1.0f / dtot;
    int l = c * CHK + (it << 5) + il;
    const float* na = &numA[grow * HD + (dg << 3)];
    float* op = &ctx[((size_t)b * SEQ + l) * DMODEL + h * HD + (dg << 3)];
#pragma unroll
    for (int jd = 0; jd < 8; ++jd) op[jd] = (na[jd] + acc[jd]) * inv;
  }
}

// ---------------- launch ----------------
extern "C" void kernel_launch(void* const* d_in, const int* in_sizes, int n_in,
                              void* d_out, int out_size, void* d_ws, size_t ws_size,
                              hipStream_t stream) {
  (void)in_sizes; (void)n_in; (void)out_size;
  const float* query = (const float*)d_in[0];
  const float* key_  = (const float*)d_in[1];
  const float* value = (const float*)d_in[2];
  const float* Wq = (const float*)d_in[3];
  const float* bq = (const float*)d_in[4];
  const float* Wk = (const float*)d_in[5];
  const float* bk = (const float*)d_in[6];
  const float* Wv = (const float*)d_in[7];
  const float* bv = (const float*)d_in[8];
  const float* Wo = (const float*)d_in[9];
  const float* bo = (const float*)d_in[10];
  const float* rf = (const float*)d_in[11];

  constexpr size_t SZQKV = (size_t)NROWS * DMODEL * 4;           // 16.78 MB
  constexpr size_t SZP   = (size_t)NBH * SEQ * NRF * 2;          // 34.87 MB (bf16)
  constexpr size_t SZSS  = (size_t)NBH * NCH * NRF * HD * 4;     // 34.87 MB
  constexpr size_t SZKS  = (size_t)NBH * NCH * NRF * 4;
  constexpr size_t SZHK  = (size_t)NBH * SEQ * 4;
  constexpr size_t SZNUMA = (size_t)NBH * SEQ * HD * 4;

  constexpr size_t O_Q = 0;
  constexpr size_t O_K = O_Q + SZQKV;
  constexpr size_t O_V = O_K + SZQKV;
  constexpr size_t O_QP = O_V + SZQKV;
  constexpr size_t O_KP = O_QP + SZP;
  constexpr size_t O_SS = O_KP + SZP;
  constexpr size_t O_KS = O_SS + SZSS;
  constexpr size_t O_HK = O_KS + SZKS;
  constexpr size_t O_PM = O_HK + SZHK;
  constexpr size_t O_KST = O_PM + (size_t)NROWS * 4;
  constexpr size_t O_NUMA = O_KST + 256;
  constexpr size_t O_DENA = O_NUMA + SZNUMA;
  constexpr size_t O_CTX = O_DENA + SZHK;
  constexpr size_t O_END = O_CTX + SZQKV;
  if (ws_size < O_END) return;  // needs ~190 MB scratch

  char* w = (char*)d_ws;
  float* Q = (float*)(w + O_Q);
  float* Kproj = (float*)(w + O_K);
  float* Vproj = (float*)(w + O_V);
  __hip_bfloat16* Qp = (__hip_bfloat16*)(w + O_QP);
  __hip_bfloat16* Kp = (__hip_bfloat16*)(w + O_KP);
  float* Ssum = (float*)(w + O_SS);
  float* ksum = (float*)(w + O_KS);
  float* hkbuf = (float*)(w + O_HK);
  float* pmax = (float*)(w + O_PM);
  float* kstab = (float*)(w + O_KST);
  float* numA = (float*)(w + O_NUMA);
  float* denA = (float*)(w + O_DENA);
  float* ctx = (float*)(w + O_CTX);

  gemm_bias_f32<<<dim3(16, 64), 256, 0, stream>>>(query, Wq, bq, Q);
  gemm_bias_f32<<<dim3(16, 64), 256, 0, stream>>>(key_, Wk, bk, Kproj);
  gemm_bias_f32<<<dim3(16, 64), 256, 0, stream>>>(value, Wv, bv, Vproj);
  hk_kernel<<<NROWS, 256, 0, stream>>>(Kproj, hkbuf, pmax);
  maxreduce_kernel<<<1, 256, 0, stream>>>(pmax, kstab);
  featmap_kernel<<<dim3(SEQ / 32, NBH, 2), 256, 0, stream>>>(Q, Kproj, rf, hkbuf,
                                                             kstab, Qp, Kp);
  chunksum_kernel<<<dim3(NCH, NBH), 256, 0, stream>>>(Kp, Vproj, Ssum, ksum);
  prefix_S_kernel<<<(NBH * NRF * HD + 255) / 256, 256, 0, stream>>>(Ssum);
  prefix_k_kernel<<<(NBH * NRF + 255) / 256, 256, 0, stream>>>(ksum);
  inter_kernel<<<dim3(NCH, NBH), 256, 0, stream>>>(Qp, Ssum, ksum, numA, denA);
  intra_kernel<<<dim3(NCH, NBH), 256, 0, stream>>>(Qp, Kp, Vproj, numA, denA, ctx);
  gemm_bias_f32<<<dim3(16, 64), 256, 0, stream>>>(ctx, Wo, bo, (float*)d_out);
}

// Round 2
// 550.353 us; speedup vs baseline: 2.1902x; 2.1902x over previous
//
#include <hip/hip_runtime.h>
#include <hip/hip_bf16.h>

#define BATCH 2
#define SEQ 2048
#define DMODEL 1024
#define NH 16
#define HD 64
#define NRF 266
#define NRFP 288   // padded feature dim (multiple of 32), cols [266,288) are zero
#define CHK 128
#define NCH 16
#define NBH 32
#define NROWS 4096  // BATCH*SEQ

constexpr float SCAL = 0.17677669529663687f;   // DMODEL^-0.25
constexpr float SCAL2 = 0.03125f;              // SCAL^2 = DMODEL^-0.5
constexpr float CNORM = 0.06131393094576169f;  // 1/sqrt(NRF)
constexpr float KEPS = 1e-4f;

typedef short bf16x8 __attribute__((ext_vector_type(8)));
typedef float f32x4 __attribute__((ext_vector_type(4)));

__device__ __forceinline__ short f2bs(float v) {
  __hip_bfloat16 h = __float2bfloat16(v);
  return *reinterpret_cast<short*>(&h);
}
__device__ __forceinline__ float bs2f(short s) {
  __hip_bfloat16 h;
  *reinterpret_cast<short*>(&h) = s;
  return __bfloat162float(h);
}
__device__ __forceinline__ void gload_lds16(const void* g, void* l) {
  __builtin_amdgcn_global_load_lds(
      (const __attribute__((address_space(1))) void*)g,
      (__attribute__((address_space(3))) void*)l, 16, 0, 0);
}

// ---------------- f32 -> bf16 convert ----------------
__global__ __launch_bounds__(256) void f32_to_bf16_k(const float* __restrict__ x,
                                                     short* __restrict__ y, int n) {
  int i = (blockIdx.x * 256 + threadIdx.x) * 8;
  if (i >= n) return;
  float4 a = *(const float4*)&x[i];
  float4 b = *(const float4*)&x[i + 4];
  bf16x8 o;
  o[0] = f2bs(a.x); o[1] = f2bs(a.y); o[2] = f2bs(a.z); o[3] = f2bs(a.w);
  o[4] = f2bs(b.x); o[5] = f2bs(b.y); o[6] = f2bs(b.z); o[7] = f2bs(b.w);
  *(bf16x8*)&y[i] = o;
}

// ---------------- W[K][N] f32 -> Wt[N][K] bf16 ----------------
__global__ __launch_bounds__(256) void transpose_bf16(const float* __restrict__ W,
                                                      short* __restrict__ Wt) {
  __shared__ float t[32][33];
  int k0 = blockIdx.y << 5, n0 = blockIdx.x << 5;
  int tx = threadIdx.x & 31, ty = threadIdx.x >> 5;  // ty 0..7
#pragma unroll
  for (int rr = 0; rr < 4; ++rr) {
    int r = ty + (rr << 3);
    t[r][tx] = W[(size_t)(k0 + r) * DMODEL + n0 + tx];
  }
  __syncthreads();
#pragma unroll
  for (int rr = 0; rr < 4; ++rr) {
    int r = ty + (rr << 3);
    Wt[(size_t)(n0 + r) * DMODEL + k0 + tx] = f2bs(t[tx][r]);
  }
}

// ---------------- MFMA GEMM: C[M x 1024] = A(bf16 [M][1024]) @ Bt(bf16 [1024][1024])^T + bias
// BM=128 BN=64 BK=64, 4 waves (2x2), XOR-swizzled LDS, global_load_lds staging.
template <bool OUTBF>
__global__ __launch_bounds__(256) void gemm_bt(const short* __restrict__ A,
                                               const short* __restrict__ Bt,
                                               const float* __restrict__ bias,
                                               void* __restrict__ C) {
  __shared__ short As[128 * 64];
  __shared__ short Bs[64 * 64];
  int tid = threadIdx.x;
  int bm = blockIdx.y << 7, bn = blockIdx.x << 6;
  int lane = tid & 63, wid = tid >> 6;
  int wr = wid >> 1, wc = wid & 1;  // wave rows: wr*64..+63, cols: wc*32..+31
  f32x4 acc[4][2];
#pragma unroll
  for (int m = 0; m < 4; ++m)
#pragma unroll
    for (int n = 0; n < 2; ++n) acc[m][n] = f32x4{0.f, 0.f, 0.f, 0.f};

  for (int k0 = 0; k0 < DMODEL; k0 += 64) {
    __syncthreads();
#pragma unroll
    for (int i = 0; i < 4; ++i) {  // A tile: 128x64 bf16 = 16KB = 4 staged chunks
      int e = tid * 8 + i * 2048;
      int row = e >> 6;
      int k = (e & 63) ^ ((row & 7) << 3);
      gload_lds16(A + (size_t)(bm + row) * DMODEL + k0 + k,
                  &As[(tid >> 6) * 512 + i * 2048]);
    }
#pragma unroll
    for (int i = 0; i < 2; ++i) {  // B tile: 64x64 bf16 = 8KB
      int e = tid * 8 + i * 2048;
      int row = e >> 6;
      int k = (e & 63) ^ ((row & 7) << 3);
      gload_lds16(Bt + (size_t)(bn + row) * DMODEL + k0 + k,
                  &Bs[(tid >> 6) * 512 + i * 2048]);
    }
    __syncthreads();
#pragma unroll
    for (int ks = 0; ks < 2; ++ks) {
      int kb = ks * 32 + ((lane >> 4) << 3);
      bf16x8 af[4], bfv[2];
#pragma unroll
      for (int mf = 0; mf < 4; ++mf) {
        int row = wr * 64 + mf * 16 + (lane & 15);
        af[mf] = *(const bf16x8*)&As[row * 64 + (kb ^ ((row & 7) << 3))];
      }
#pragma unroll
      for (int nf = 0; nf < 2; ++nf) {
        int row = wc * 32 + nf * 16 + (lane & 15);
        bfv[nf] = *(const bf16x8*)&Bs[row * 64 + (kb ^ ((row & 7) << 3))];
      }
#pragma unroll
      for (int mf = 0; mf < 4; ++mf)
#pragma unroll
        for (int nf = 0; nf < 2; ++nf)
          acc[mf][nf] = __builtin_amdgcn_mfma_f32_16x16x32_bf16(af[mf], bfv[nf],
                                                                acc[mf][nf], 0, 0, 0);
    }
  }
  // C layout: col = lane&15, row = (lane>>4)*4 + reg
  int rbase = bm + wr * 64 + ((lane >> 4) << 2);
  int cbase = bn + wc * 32 + (lane & 15);
#pragma unroll
  for (int nf = 0; nf < 2; ++nf) {
    int col = cbase + nf * 16;
    float bv = bias[col];
#pragma unroll
    for (int mf = 0; mf < 4; ++mf)
#pragma unroll
      for (int r = 0; r < 4; ++r) {
        int row = rbase + mf * 16 + r;
        float v = acc[mf][nf][r] + bv;
        if (OUTBF)
          ((short*)C)[(size_t)row * DMODEL + col] = f2bs(v);
        else
          ((float*)C)[(size_t)row * DMODEL + col] = v;
      }
  }
}

// ---------------- h_k per (b,h,l) + per-block max (bf16 K input) ----------------
__global__ __launch_bounds__(256) void hk_kernel(const short* __restrict__ Kb,
                                                 float* __restrict__ hkbuf,
                                                 float* __restrict__ pmax) {
  int n = blockIdx.x;  // b*SEQ + l
  int tid = threadIdx.x;
  short4 kv = *(const short4*)(Kb + (size_t)n * DMODEL + tid * 4);
  float x0 = bs2f(kv.x), x1 = bs2f(kv.y), x2 = bs2f(kv.z), x3 = bs2f(kv.w);
  float ss = x0 * x0 + x1 * x1 + x2 * x2 + x3 * x3;
#pragma unroll
  for (int off = 8; off >= 1; off >>= 1) ss += __shfl_xor(ss, off, 16);
  float hkv = -0.5f * SCAL2 * ss;
  int h = tid >> 4;
  if ((tid & 15) == 0) {
    int b = n >> 11, l = n & (SEQ - 1);
    hkbuf[((size_t)(b * NH + h)) * SEQ + l] = hkv;
  }
  __shared__ float red[256];
  red[tid] = hkv;
  __syncthreads();
  for (int s = 128; s > 0; s >>= 1) {
    if (tid < s) red[tid] = fmaxf(red[tid], red[tid + s]);
    __syncthreads();
  }
  if (tid == 0) pmax[n] = red[0];
}

__global__ __launch_bounds__(256) void maxreduce_kernel(const float* __restrict__ pmax,
                                                        float* __restrict__ kstab) {
  int tid = threadIdx.x;
  float m = -3.0e38f;
  for (int i = tid; i < NROWS; i += 256) m = fmaxf(m, pmax[i]);
  __shared__ float red[256];
  red[tid] = m;
  __syncthreads();
  for (int s = 128; s > 0; s >>= 1) {
    if (tid < s) red[tid] = fmaxf(red[tid], red[tid + s]);
    __syncthreads();
  }
  if (tid == 0) *kstab = red[0];
}

// ---------------- feature map (bf16 in, padded bf16 out, stride NRFP) ----------------
__global__ __launch_bounds__(256) void featmap_kernel(
    const short* __restrict__ Qproj, const short* __restrict__ Kproj,
    const float* __restrict__ rf, const float* __restrict__ hkbuf,
    const float* __restrict__ kstab, short* __restrict__ Qp, short* __restrict__ Kp) {
  __shared__ float rfs[NRF][65];
  __shared__ float qsh[32][65];
  int isK = blockIdx.z;
  const short* X = isK ? Kproj : Qproj;
  short* O = isK ? Kp : Qp;
  int bh = blockIdx.y, b = bh >> 4, h = bh & 15;
  int l0 = blockIdx.x << 5;
  int tid = threadIdx.x;
  for (int idx = tid; idx < NRF * HD; idx += 256)
    rfs[idx >> 6][idx & 63] = rf[idx];
  for (int idx = tid; idx < 32 * HD; idx += 256) {
    int r = idx >> 6, d = idx & 63;
    qsh[r][d] = bs2f(X[((size_t)b * SEQ + l0 + r) * DMODEL + h * HD + d]) * SCAL;
  }
  __syncthreads();
  int rg = tid >> 6, mg = tid & 63;
  float acc[8][5];
#pragma unroll
  for (int i = 0; i < 8; ++i)
#pragma unroll
    for (int j = 0; j < 5; ++j) acc[i][j] = 0.f;
  for (int d = 0; d < HD; ++d) {
    float qv[8];
#pragma unroll
    for (int rr = 0; rr < 8; ++rr) qv[rr] = qsh[rg + (rr << 2)][d];
    float rv[5];
#pragma unroll
    for (int jm = 0; jm < 4; ++jm) rv[jm] = rfs[mg + (jm << 6)][d];
    rv[4] = (mg < 10) ? rfs[mg + 256][d] : 0.f;
#pragma unroll
    for (int rr = 0; rr < 8; ++rr)
#pragma unroll
      for (int jm = 0; jm < 5; ++jm) acc[rr][jm] += qv[rr] * rv[jm];
  }
  float ksv = isK ? *kstab : 0.f;
#pragma unroll
  for (int rr = 0; rr < 8; ++rr) {
    int l = l0 + rg + (rr << 2);
    float addk = isK ? (hkbuf[(size_t)bh * SEQ + l] - ksv) : 0.f;
    size_t rowb = ((size_t)bh * SEQ + l) * NRFP;
#pragma unroll
    for (int jm = 0; jm < 5; ++jm) {
      int m = mg + (jm << 6);
      if (m < NRF)
        O[rowb + m] = f2bs(CNORM * (expf(acc[rr][jm] + addk) + KEPS));
      else if (m < NRFP)
        O[rowb + m] = 0;
    }
  }
}

// ---------------- per-chunk sums -> Schunk bf16 [bh][c][NRFP][64], ksum f32 ----------------
__global__ __launch_bounds__(256) void chunksum_kernel(
    const short* __restrict__ Kp, const short* __restrict__ Vb,
    short* __restrict__ Schunk, float* __restrict__ ksum) {
  int c = blockIdx.x, bh = blockIdx.y;
  int b = bh >> 4, h = bh & 15;
  __shared__ float ksh[32][NRF];
  __shared__ float vsh[32][HD];
  int tid = threadIdx.x;
  int mg = tid >> 4, dg = tid & 15;
  float acc[17][4];
#pragma unroll
  for (int jm = 0; jm < 17; ++jm)
#pragma unroll
    for (int jd = 0; jd < 4; ++jd) acc[jm][jd] = 0.f;
  float kacc[17];
#pragma unroll
  for (int jm = 0; jm < 17; ++jm) kacc[jm] = 0.f;
  for (int it = 0; it < 4; ++it) {
    __syncthreads();
    int i0 = c * CHK + (it << 5);
    for (int idx = tid; idx < 32 * NRF; idx += 256) {
      int i = idx / NRF, m = idx - i * NRF;
      ksh[i][m] = bs2f(Kp[((size_t)bh * SEQ + i0 + i) * NRFP + m]);
    }
    for (int idx = tid; idx < 32 * HD; idx += 256) {
      int i = idx >> 6, d = idx & 63;
      vsh[i][d] = bs2f(Vb[((size_t)b * SEQ + i0 + i) * DMODEL + h * HD + d]);
    }
    __syncthreads();
    for (int i = 0; i < 32; ++i) {
      float4 v4 = *(const float4*)&vsh[i][dg << 2];
#pragma unroll
      for (int jm = 0; jm < 16; ++jm) {
        float kv = ksh[i][mg + (jm << 4)];
        acc[jm][0] += kv * v4.x; acc[jm][1] += kv * v4.y;
        acc[jm][2] += kv * v4.z; acc[jm][3] += kv * v4.w;
      }
      if (mg < 10) {
        float kv = ksh[i][mg + 256];
        acc[16][0] += kv * v4.x; acc[16][1] += kv * v4.y;
        acc[16][2] += kv * v4.z; acc[16][3] += kv * v4.w;
      }
      if (dg == 0) {
#pragma unroll
        for (int jm = 0; jm < 16; ++jm) kacc[jm] += ksh[i][mg + (jm << 4)];
        if (mg < 10) kacc[16] += ksh[i][mg + 256];
      }
    }
  }
  size_t sbase = ((size_t)bh * NCH + c) * (size_t)(NRFP * HD);
  size_t kbase = ((size_t)bh * NCH + c) * (size_t)NRF;
#pragma unroll
  for (int jm = 0; jm < 16; ++jm) {
    int m = mg + (jm << 4);
    short4 o = make_short4(f2bs(acc[jm][0]), f2bs(acc[jm][1]),
                           f2bs(acc[jm][2]), f2bs(acc[jm][3]));
    *(short4*)&Schunk[sbase + (size_t)m * HD + (dg << 2)] = o;
    if (dg == 0) ksum[kbase + m] = kacc[jm];
  }
  if (mg < 10) {
    int m = mg + 256;
    short4 o = make_short4(f2bs(acc[16][0]), f2bs(acc[16][1]),
                           f2bs(acc[16][2]), f2bs(acc[16][3]));
    *(short4*)&Schunk[sbase + (size_t)m * HD + (dg << 2)] = o;
    if (dg == 0) ksum[kbase + m] = kacc[16];
  }
  // zero padded feature rows [266,288)
  for (int idx = tid; idx < (NRFP - NRF) * HD; idx += 256) {
    int m = NRF + (idx >> 6), d = idx & 63;
    Schunk[sbase + (size_t)m * HD + d] = 0;
  }
}

// ---------------- exclusive prefix over chunks: Schunk bf16 -> Spref bf16 (f32 accum) ----------------
__global__ __launch_bounds__(256) void prefix_S_bf(const short* __restrict__ Sc,
                                                   short* __restrict__ Sp) {
  int e = blockIdx.x * 256 + threadIdx.x;  // 0 .. 288*64-1 (grid.x = 72 exact)
  int bh = blockIdx.y;
  size_t base = (size_t)bh * NCH * (NRFP * HD) + e;
  float a = 0.f;
#pragma unroll
  for (int c = 0; c < NCH; ++c) {
    size_t idx = base + (size_t)c * (NRFP * HD);
    float v = bs2f(Sc[idx]);
    Sp[idx] = f2bs(a);
    a += v;
  }
}

__global__ void prefix_k_kernel(float* __restrict__ ksum) {
  int tid = blockIdx.x * 256 + threadIdx.x;
  if (tid >= NBH * NRF) return;
  int bh = tid / NRF;
  int m = tid - bh * NRF;
  size_t base = (size_t)bh * NCH * NRF + m;
  float a = 0.f;
#pragma unroll
  for (int c = 0; c < NCH; ++c) {
    size_t idx = base + (size_t)c * NRF;
    float v = ksum[idx];
    ksum[idx] = a;
    a += v;
  }
}

// ---------------- inter-chunk via MFMA: numA[128x64] = Q'[128x288] @ Sprev[288x64]; denA VALU ----------------
__global__ __launch_bounds__(256) void inter_mfma(
    const short* __restrict__ Qp, const short* __restrict__ Sp,
    const float* __restrict__ ksum, float* __restrict__ numA,
    float* __restrict__ denA) {
  int c = blockIdx.x, bh = blockIdx.y;
  __shared__ short Bs[64 * 296];  // transposed S: [d][m], padded stride 296
  __shared__ float ks[272];
  int tid = threadIdx.x, lane = tid & 63, wid = tid >> 6;
  const short* Spb = Sp + ((size_t)bh * NCH + c) * (size_t)(NRFP * HD);
  for (int idx = tid; idx < NRFP * HD; idx += 256) {
    int m = idx >> 6, d = idx & 63;
    Bs[d * 296 + m] = Spb[idx];
  }
  const float* ksb = ksum + ((size_t)bh * NCH + c) * (size_t)NRF;
  for (int idx = tid; idx < NRF; idx += 256) ks[idx] = ksb[idx];
  __syncthreads();
  int row0 = wid * 32;
  const short* Arow = Qp + ((size_t)bh * SEQ + (size_t)c * CHK + row0) * NRFP;
  f32x4 acc[2][4];
#pragma unroll
  for (int m = 0; m < 2; ++m)
#pragma unroll
    for (int n = 0; n < 4; ++n) acc[m][n] = f32x4{0.f, 0.f, 0.f, 0.f};
#pragma unroll
  for (int k9 = 0; k9 < 9; ++k9) {
    int kb = k9 * 32 + ((lane >> 4) << 3);
    bf16x8 af[2], bfv[4];
#pragma unroll
    for (int mf = 0; mf < 2; ++mf)
      af[mf] = *(const bf16x8*)(Arow + (size_t)(mf * 16 + (lane & 15)) * NRFP + kb);
#pragma unroll
    for (int nf = 0; nf < 4; ++nf)
      bfv[nf] = *(const bf16x8*)&Bs[(nf * 16 + (lane & 15)) * 296 + kb];
#pragma unroll
    for (int mf = 0; mf < 2; ++mf)
#pragma unroll
      for (int nf = 0; nf < 4; ++nf)
        acc[mf][nf] = __builtin_amdgcn_mfma_f32_16x16x32_bf16(af[mf], bfv[nf],
                                                              acc[mf][nf], 0, 0, 0);
  }
  size_t nb = ((size_t)bh * SEQ + (size_t)c * CHK + row0) * HD;
#pragma unroll
  for (int mf = 0; mf < 2; ++mf)
#pragma unroll
    for (int nf = 0; nf < 4; ++nf)
#pragma unroll
      for (int r = 0; r < 4; ++r) {
        int row = mf * 16 + ((lane >> 4) << 2) + r;
        int col = nf * 16 + (lane & 15);
        numA[nb + (size_t)row * HD + col] = acc[mf][nf][r];
      }
  // denominator: q'_row . ksum_prefix
  int r = tid >> 1, half = tid & 1;
  const short* qr = Qp + ((size_t)bh * SEQ + (size_t)c * CHK + r) * NRFP;
  float s = 0.f;
  int m0 = half * 133;
  for (int m = m0; m < m0 + 133; ++m) s += bs2f(qr[m]) * ks[m];
  s += __shfl_xor(s, 1);
  if (!half) denA[(size_t)bh * SEQ + (size_t)c * CHK + r] = s;
}

// ---------------- intra-chunk: masked (Q'K'^T) @ V, rowsum; finalize ctx (bf16) ----------------
__global__ __launch_bounds__(256) void intra_kernel(
    const short* __restrict__ Qp, const short* __restrict__ Kp,
    const short* __restrict__ Vb, const float* __restrict__ numA,
    const float* __restrict__ denA, short* __restrict__ ctxb) {
  int c = blockIdx.x, bh = blockIdx.y;
  int b = bh >> 4, h = bh & 15;
  __shared__ float qsh[32][NRF];
  __shared__ float ksh[32][NRF];
  __shared__ float vsh[32][HD];
  __shared__ float Psh[32][33];
  int tid = threadIdx.x;
  int il = tid >> 3;
  int dg = tid & 7;
  int iq = tid >> 4, jp = tid & 15;
  size_t rowb = (size_t)bh * SEQ + (size_t)c * CHK;
  for (int it = 0; it < 4; ++it) {
    __syncthreads();
    for (int idx = tid; idx < 32 * NRF; idx += 256) {
      int i = idx / NRF, m = idx - i * NRF;
      qsh[i][m] = bs2f(Qp[(rowb + (it << 5) + i) * NRFP + m]);
    }
    __syncthreads();
    float acc[8];
#pragma unroll
    for (int jd = 0; jd < 8; ++jd) acc[jd] = 0.f;
    float den = 0.f;
    for (int jt = 0; jt <= it; ++jt) {
      __syncthreads();
      for (int idx = tid; idx < 32 * NRF; idx += 256) {
        int j = idx / NRF, m = idx - j * NRF;
        ksh[j][m] = bs2f(Kp[(rowb + (jt << 5) + j) * NRFP + m]);
      }
      for (int idx = tid; idx < 32 * HD; idx += 256) {
        int j = idx >> 6, dd = idx & 63;
        vsh[j][dd] = bs2f(
            Vb[((size_t)b * SEQ + (size_t)c * CHK + (jt << 5) + j) * DMODEL + h * HD + dd]);
      }
      __syncthreads();
      int i0 = iq << 1, j0 = jp << 1;
      float p00 = 0.f, p01 = 0.f, p10 = 0.f, p11 = 0.f;
#pragma unroll 2
      for (int m = 0; m < NRF; ++m) {
        float q0 = qsh[i0][m], q1 = qsh[i0 + 1][m];
        float k0 = ksh[j0][m], k1 = ksh[j0 + 1][m];
        p00 += q0 * k0; p01 += q0 * k1;
        p10 += q1 * k0; p11 += q1 * k1;
      }
      if (jt == it) {
        if (j0 > i0) p00 = 0.f;
        if (j0 + 1 > i0) p01 = 0.f;
        if (j0 > i0 + 1) p10 = 0.f;
        if (j0 + 1 > i0 + 1) p11 = 0.f;
      }
      Psh[i0][j0] = p00;
      Psh[i0][j0 + 1] = p01;
      Psh[i0 + 1][j0] = p10;
      Psh[i0 + 1][j0 + 1] = p11;
      __syncthreads();
#pragma unroll 4
      for (int j = 0; j < 32; ++j) {
        float p = Psh[il][j];
        den += p;
        const float* vr = &vsh[j][dg << 3];
#pragma unroll
        for (int jd = 0; jd < 8; ++jd) acc[jd] += p * vr[jd];
      }
    }
    size_t grow = rowb + (it << 5) + il;
    float dtot = denA[grow] + den;
    float inv = 1.0f / dtot;
    int l = c * CHK + (it << 5) + il;
    const float* na = &numA[grow * HD + (dg << 3)];
    short* op = &ctxb[((size_t)b * SEQ + l) * DMODEL + h * HD + (dg << 3)];
#pragma unroll
    for (int jd = 0; jd < 8; ++jd) op[jd] = f2bs((na[jd] + acc[jd]) * inv);
  }
}

// ---------------- launch ----------------
extern "C" void kernel_launch(void* const* d_in, const int* in_sizes, int n_in,
                              void* d_out, int out_size, void* d_ws, size_t ws_size,
                              hipStream_t stream) {
  (void)in_sizes; (void)n_in; (void)out_size;
  const float* query = (const float*)d_in[0];
  const float* key_  = (const float*)d_in[1];
  const float* value = (const float*)d_in[2];
  const float* Wq = (const float*)d_in[3];
  const float* bq = (const float*)d_in[4];
  const float* Wk = (const float*)d_in[5];
  const float* bk = (const float*)d_in[6];
  const float* Wv = (const float*)d_in[7];
  const float* bv = (const float*)d_in[8];
  const float* Wo = (const float*)d_in[9];
  const float* bo = (const float*)d_in[10];
  const float* rf = (const float*)d_in[11];

  constexpr size_t SZ_INBF = (size_t)NROWS * DMODEL * 2;         // 8,388,608
  constexpr size_t SZ_QP   = (size_t)NBH * SEQ * NRFP * 2;       // 37,748,736
  constexpr size_t SZ_WT   = (size_t)DMODEL * DMODEL * 2;        // 2,097,152
  constexpr size_t SZ_SCH  = (size_t)NBH * NCH * NRFP * HD * 2;  // 18,874,368
  constexpr size_t SZ_KS   = (size_t)NBH * NCH * NRF * 4;
  constexpr size_t SZ_HK   = (size_t)NBH * SEQ * 4;
  constexpr size_t SZ_NUMA = (size_t)NBH * SEQ * HD * 4;         // 16,777,216

  // Qp region aliases the (dead-by-then) Qbf/Kbf/Vbf inputs
  constexpr size_t O_QP   = 0;                      // size SZ_QP (Qbf@0, Kbf@SZ_INBF, Vbf@2*SZ_INBF inside)
  constexpr size_t O_KP   = O_QP + SZ_QP;
  constexpr size_t O_WT   = O_KP + SZ_QP;           // 4 weight transposes
  constexpr size_t O_QPR  = O_WT + 4 * SZ_WT;
  constexpr size_t O_KPR  = O_QPR + SZ_INBF;
  constexpr size_t O_VPR  = O_KPR + SZ_INBF;
  constexpr size_t O_SCH  = O_VPR + SZ_INBF;
  constexpr size_t O_SPR  = O_SCH + SZ_SCH;
  constexpr size_t O_KSUM = O_SPR + SZ_SCH;
  constexpr size_t O_HK   = O_KSUM + SZ_KS;
  constexpr size_t O_PMAX = O_HK + SZ_HK;
  constexpr size_t O_KST  = O_PMAX + (size_t)NROWS * 4;
  constexpr size_t O_NUMA = O_KST + 256;
  constexpr size_t O_DENA = O_NUMA + SZ_NUMA;
  constexpr size_t O_CTXB = O_DENA + SZ_HK;
  constexpr size_t O_END  = O_CTXB + SZ_INBF;       // ~173 MB
  if (ws_size < O_END) return;

  char* w = (char*)d_ws;
  short* Qbf = (short*)(w + O_QP);
  short* Kbf = (short*)(w + O_QP + SZ_INBF);
  short* Vbf = (short*)(w + O_QP + 2 * SZ_INBF);
  short* Qp  = (short*)(w + O_QP);
  short* Kp  = (short*)(w + O_KP);
  short* WtQ = (short*)(w + O_WT);
  short* WtK = (short*)(w + O_WT + SZ_WT);
  short* WtV = (short*)(w + O_WT + 2 * SZ_WT);
  short* WtO = (short*)(w + O_WT + 3 * SZ_WT);
  short* Qpr = (short*)(w + O_QPR);
  short* Kpr = (short*)(w + O_KPR);
  short* Vpr = (short*)(w + O_VPR);
  short* Sch = (short*)(w + O_SCH);
  short* Spr = (short*)(w + O_SPR);
  float* ksum = (float*)(w + O_KSUM);
  float* hkbuf = (float*)(w + O_HK);
  float* pmax = (float*)(w + O_PMAX);
  float* kstab = (float*)(w + O_KST);
  float* numA = (float*)(w + O_NUMA);
  float* denA = (float*)(w + O_DENA);
  short* ctxb = (short*)(w + O_CTXB);

  constexpr int NEL = NROWS * DMODEL;
  f32_to_bf16_k<<<NEL / (256 * 8), 256, 0, stream>>>(query, Qbf, NEL);
  f32_to_bf16_k<<<NEL / (256 * 8), 256, 0, stream>>>(key_, Kbf, NEL);
  f32_to_bf16_k<<<NEL / (256 * 8), 256, 0, stream>>>(value, Vbf, NEL);
  transpose_bf16<<<dim3(32, 32), 256, 0, stream>>>(Wq, WtQ);
  transpose_bf16<<<dim3(32, 32), 256, 0, stream>>>(Wk, WtK);
  transpose_bf16<<<dim3(32, 32), 256, 0, stream>>>(Wv, WtV);
  transpose_bf16<<<dim3(32, 32), 256, 0, stream>>>(Wo, WtO);
  gemm_bt<true><<<dim3(16, 32), 256, 0, stream>>>(Qbf, WtQ, bq, Qpr);
  gemm_bt<true><<<dim3(16, 32), 256, 0, stream>>>(Kbf, WtK, bk, Kpr);
  gemm_bt<true><<<dim3(16, 32), 256, 0, stream>>>(Vbf, WtV, bv, Vpr);
  hk_kernel<<<NROWS, 256, 0, stream>>>(Kpr, hkbuf, pmax);
  maxreduce_kernel<<<1, 256, 0, stream>>>(pmax, kstab);
  featmap_kernel<<<dim3(SEQ / 32, NBH, 2), 256, 0, stream>>>(Qpr, Kpr, rf, hkbuf,
                                                             kstab, Qp, Kp);
  chunksum_kernel<<<dim3(NCH, NBH), 256, 0, stream>>>(Kp, Vpr, Sch, ksum);
  prefix_S_bf<<<dim3(NRFP * HD / 256, NBH), 256, 0, stream>>>(Sch, Spr);
  prefix_k_kernel<<<(NBH * NRF + 255) / 256, 256, 0, stream>>>(ksum);
  inter_mfma<<<dim3(NCH, NBH), 256, 0, stream>>>(Qp, Spr, ksum, numA, denA);
  intra_kernel<<<dim3(NCH, NBH), 256, 0, stream>>>(Qp, Kp, Vpr, numA, denA, ctxb);
  gemm_bt<false><<<dim3(16, 32), 256, 0, stream>>>(ctxb, WtO, bo, d_out);
}

// Round 3
// 371.538 us; speedup vs baseline: 3.2443x; 1.4813x over previous
//
#include <hip/hip_runtime.h>
#include <hip/hip_bf16.h>

#define BATCH 2
#define SEQ 2048
#define DMODEL 1024
#define NH 16
#define HD 64
#define NRF 266
#define NRFP 288   // padded feature dim (multiple of 32), cols [266,288) are zero
#define CHK 128
#define NCH 16
#define NBH 32
#define NROWS 4096  // BATCH*SEQ

constexpr float SCAL = 0.17677669529663687f;   // DMODEL^-0.25
constexpr float SCAL2 = 0.03125f;              // SCAL^2 = DMODEL^-0.5
constexpr float CNORM = 0.06131393094576169f;  // 1/sqrt(NRF)
constexpr float KEPS = 1e-4f;

typedef short bf16x8 __attribute__((ext_vector_type(8)));
typedef float f32x4 __attribute__((ext_vector_type(4)));

__device__ __forceinline__ short f2bs(float v) {
  __hip_bfloat16 h = __float2bfloat16(v);
  return *reinterpret_cast<short*>(&h);
}
__device__ __forceinline__ float bs2f(short s) {
  __hip_bfloat16 h;
  *reinterpret_cast<short*>(&h) = s;
  return __bfloat162float(h);
}
__device__ __forceinline__ void gload_lds16(const void* g, void* l) {
  __builtin_amdgcn_global_load_lds(
      (const __attribute__((address_space(1))) void*)g,
      (__attribute__((address_space(3))) void*)l, 16, 0, 0);
}

// ---------------- f32 -> bf16 convert ----------------
__global__ __launch_bounds__(256) void f32_to_bf16_k(const float* __restrict__ x,
                                                     short* __restrict__ y, int n) {
  int i = (blockIdx.x * 256 + threadIdx.x) * 8;
  if (i >= n) return;
  float4 a = *(const float4*)&x[i];
  float4 b = *(const float4*)&x[i + 4];
  bf16x8 o;
  o[0] = f2bs(a.x); o[1] = f2bs(a.y); o[2] = f2bs(a.z); o[3] = f2bs(a.w);
  o[4] = f2bs(b.x); o[5] = f2bs(b.y); o[6] = f2bs(b.z); o[7] = f2bs(b.w);
  *(bf16x8*)&y[i] = o;
}

// ---------------- W[K][N] f32 -> Wt[N][K] bf16 ----------------
__global__ __launch_bounds__(256) void transpose_bf16(const float* __restrict__ W,
                                                      short* __restrict__ Wt) {
  __shared__ float t[32][33];
  int k0 = blockIdx.y << 5, n0 = blockIdx.x << 5;
  int tx = threadIdx.x & 31, ty = threadIdx.x >> 5;  // ty 0..7
#pragma unroll
  for (int rr = 0; rr < 4; ++rr) {
    int r = ty + (rr << 3);
    t[r][tx] = W[(size_t)(k0 + r) * DMODEL + n0 + tx];
  }
  __syncthreads();
#pragma unroll
  for (int rr = 0; rr < 4; ++rr) {
    int r = ty + (rr << 3);
    Wt[(size_t)(n0 + r) * DMODEL + k0 + tx] = f2bs(t[tx][r]);
  }
}

// ---------------- MFMA GEMM: C[M x 1024] = A(bf16 [M][1024]) @ Bt(bf16 [1024][1024])^T + bias
template <bool OUTBF>
__global__ __launch_bounds__(256) void gemm_bt(const short* __restrict__ A,
                                               const short* __restrict__ Bt,
                                               const float* __restrict__ bias,
                                               void* __restrict__ C) {
  __shared__ short As[128 * 64];
  __shared__ short Bs[64 * 64];
  int tid = threadIdx.x;
  int bm = blockIdx.y << 7, bn = blockIdx.x << 6;
  int lane = tid & 63, wid = tid >> 6;
  int wr = wid >> 1, wc = wid & 1;
  f32x4 acc[4][2];
#pragma unroll
  for (int m = 0; m < 4; ++m)
#pragma unroll
    for (int n = 0; n < 2; ++n) acc[m][n] = f32x4{0.f, 0.f, 0.f, 0.f};

  for (int k0 = 0; k0 < DMODEL; k0 += 64) {
    __syncthreads();
#pragma unroll
    for (int i = 0; i < 4; ++i) {
      int e = tid * 8 + i * 2048;
      int row = e >> 6;
      int k = (e & 63) ^ ((row & 7) << 3);
      gload_lds16(A + (size_t)(bm + row) * DMODEL + k0 + k,
                  &As[(tid >> 6) * 512 + i * 2048]);
    }
#pragma unroll
    for (int i = 0; i < 2; ++i) {
      int e = tid * 8 + i * 2048;
      int row = e >> 6;
      int k = (e & 63) ^ ((row & 7) << 3);
      gload_lds16(Bt + (size_t)(bn + row) * DMODEL + k0 + k,
                  &Bs[(tid >> 6) * 512 + i * 2048]);
    }
    __syncthreads();
#pragma unroll
    for (int ks = 0; ks < 2; ++ks) {
      int kb = ks * 32 + ((lane >> 4) << 3);
      bf16x8 af[4], bfv[2];
#pragma unroll
      for (int mf = 0; mf < 4; ++mf) {
        int row = wr * 64 + mf * 16 + (lane & 15);
        af[mf] = *(const bf16x8*)&As[row * 64 + (kb ^ ((row & 7) << 3))];
      }
#pragma unroll
      for (int nf = 0; nf < 2; ++nf) {
        int row = wc * 32 + nf * 16 + (lane & 15);
        bfv[nf] = *(const bf16x8*)&Bs[row * 64 + (kb ^ ((row & 7) << 3))];
      }
#pragma unroll
      for (int mf = 0; mf < 4; ++mf)
#pragma unroll
        for (int nf = 0; nf < 2; ++nf)
          acc[mf][nf] = __builtin_amdgcn_mfma_f32_16x16x32_bf16(af[mf], bfv[nf],
                                                                acc[mf][nf], 0, 0, 0);
    }
  }
  int rbase = bm + wr * 64 + ((lane >> 4) << 2);
  int cbase = bn + wc * 32 + (lane & 15);
#pragma unroll
  for (int nf = 0; nf < 2; ++nf) {
    int col = cbase + nf * 16;
    float bv = bias[col];
#pragma unroll
    for (int mf = 0; mf < 4; ++mf)
#pragma unroll
      for (int r = 0; r < 4; ++r) {
        int row = rbase + mf * 16 + r;
        float v = acc[mf][nf][r] + bv;
        if (OUTBF)
          ((short*)C)[(size_t)row * DMODEL + col] = f2bs(v);
        else
          ((float*)C)[(size_t)row * DMODEL + col] = v;
      }
  }
}

// ---------------- h_k per (b,h,l) + per-block max (bf16 K input) ----------------
__global__ __launch_bounds__(256) void hk_kernel(const short* __restrict__ Kb,
                                                 float* __restrict__ hkbuf,
                                                 float* __restrict__ pmax) {
  int n = blockIdx.x;
  int tid = threadIdx.x;
  short4 kv = *(const short4*)(Kb + (size_t)n * DMODEL + tid * 4);
  float x0 = bs2f(kv.x), x1 = bs2f(kv.y), x2 = bs2f(kv.z), x3 = bs2f(kv.w);
  float ss = x0 * x0 + x1 * x1 + x2 * x2 + x3 * x3;
#pragma unroll
  for (int off = 8; off >= 1; off >>= 1) ss += __shfl_xor(ss, off, 16);
  float hkv = -0.5f * SCAL2 * ss;
  int h = tid >> 4;
  if ((tid & 15) == 0) {
    int b = n >> 11, l = n & (SEQ - 1);
    hkbuf[((size_t)(b * NH + h)) * SEQ + l] = hkv;
  }
  __shared__ float red[256];
  red[tid] = hkv;
  __syncthreads();
  for (int s = 128; s > 0; s >>= 1) {
    if (tid < s) red[tid] = fmaxf(red[tid], red[tid + s]);
    __syncthreads();
  }
  if (tid == 0) pmax[n] = red[0];
}

__global__ __launch_bounds__(256) void maxreduce_kernel(const float* __restrict__ pmax,
                                                        float* __restrict__ kstab) {
  int tid = threadIdx.x;
  float m = -3.0e38f;
  for (int i = tid; i < NROWS; i += 256) m = fmaxf(m, pmax[i]);
  __shared__ float red[256];
  red[tid] = m;
  __syncthreads();
  for (int s = 128; s > 0; s >>= 1) {
    if (tid < s) red[tid] = fmaxf(red[tid], red[tid + s]);
    __syncthreads();
  }
  if (tid == 0) *kstab = red[0];
}

// ---------------- feature map (bf16 in, padded bf16 out, stride NRFP) ----------------
__global__ __launch_bounds__(256) void featmap_kernel(
    const short* __restrict__ Qproj, const short* __restrict__ Kproj,
    const float* __restrict__ rf, const float* __restrict__ hkbuf,
    const float* __restrict__ kstab, short* __restrict__ Qp, short* __restrict__ Kp) {
  __shared__ float rfs[NRF][65];
  __shared__ float qsh[32][65];
  int isK = blockIdx.z;
  const short* X = isK ? Kproj : Qproj;
  short* O = isK ? Kp : Qp;
  int bh = blockIdx.y, b = bh >> 4, h = bh & 15;
  int l0 = blockIdx.x << 5;
  int tid = threadIdx.x;
  for (int idx = tid; idx < NRF * HD; idx += 256)
    rfs[idx >> 6][idx & 63] = rf[idx];
  for (int idx = tid; idx < 32 * HD; idx += 256) {
    int r = idx >> 6, d = idx & 63;
    qsh[r][d] = bs2f(X[((size_t)b * SEQ + l0 + r) * DMODEL + h * HD + d]) * SCAL;
  }
  __syncthreads();
  int rg = tid >> 6, mg = tid & 63;
  float acc[8][5];
#pragma unroll
  for (int i = 0; i < 8; ++i)
#pragma unroll
    for (int j = 0; j < 5; ++j) acc[i][j] = 0.f;
  for (int d = 0; d < HD; ++d) {
    float qv[8];
#pragma unroll
    for (int rr = 0; rr < 8; ++rr) qv[rr] = qsh[rg + (rr << 2)][d];
    float rv[5];
#pragma unroll
    for (int jm = 0; jm < 4; ++jm) rv[jm] = rfs[mg + (jm << 6)][d];
    rv[4] = (mg < 10) ? rfs[mg + 256][d] : 0.f;
#pragma unroll
    for (int rr = 0; rr < 8; ++rr)
#pragma unroll
      for (int jm = 0; jm < 5; ++jm) acc[rr][jm] += qv[rr] * rv[jm];
  }
  float ksv = isK ? *kstab : 0.f;
#pragma unroll
  for (int rr = 0; rr < 8; ++rr) {
    int l = l0 + rg + (rr << 2);
    float addk = isK ? (hkbuf[(size_t)bh * SEQ + l] - ksv) : 0.f;
    size_t rowb = ((size_t)bh * SEQ + l) * NRFP;
#pragma unroll
    for (int jm = 0; jm < 5; ++jm) {
      int m = mg + (jm << 6);
      if (m < NRF)
        O[rowb + m] = f2bs(CNORM * (expf(acc[rr][jm] + addk) + KEPS));
      else if (m < NRFP)
        O[rowb + m] = 0;
    }
  }
}

// ---------------- per-chunk sums -> Schunk bf16 [bh][c][NRFP][64], ksum f32 ----------------
__global__ __launch_bounds__(256) void chunksum_kernel(
    const short* __restrict__ Kp, const short* __restrict__ Vb,
    short* __restrict__ Schunk, float* __restrict__ ksum) {
  int c = blockIdx.x, bh = blockIdx.y;
  int b = bh >> 4, h = bh & 15;
  __shared__ float ksh[32][NRF];
  __shared__ float vsh[32][HD];
  int tid = threadIdx.x;
  int mg = tid >> 4, dg = tid & 15;
  float acc[17][4];
#pragma unroll
  for (int jm = 0; jm < 17; ++jm)
#pragma unroll
    for (int jd = 0; jd < 4; ++jd) acc[jm][jd] = 0.f;
  float kacc[17];
#pragma unroll
  for (int jm = 0; jm < 17; ++jm) kacc[jm] = 0.f;
  for (int it = 0; it < 4; ++it) {
    __syncthreads();
    int i0 = c * CHK + (it << 5);
    for (int idx = tid; idx < 32 * NRF; idx += 256) {
      int i = idx / NRF, m = idx - i * NRF;
      ksh[i][m] = bs2f(Kp[((size_t)bh * SEQ + i0 + i) * NRFP + m]);
    }
    for (int idx = tid; idx < 32 * HD; idx += 256) {
      int i = idx >> 6, d = idx & 63;
      vsh[i][d] = bs2f(Vb[((size_t)b * SEQ + i0 + i) * DMODEL + h * HD + d]);
    }
    __syncthreads();
    for (int i = 0; i < 32; ++i) {
      float4 v4 = *(const float4*)&vsh[i][dg << 2];
#pragma unroll
      for (int jm = 0; jm < 16; ++jm) {
        float kv = ksh[i][mg + (jm << 4)];
        acc[jm][0] += kv * v4.x; acc[jm][1] += kv * v4.y;
        acc[jm][2] += kv * v4.z; acc[jm][3] += kv * v4.w;
      }
      if (mg < 10) {
        float kv = ksh[i][mg + 256];
        acc[16][0] += kv * v4.x; acc[16][1] += kv * v4.y;
        acc[16][2] += kv * v4.z; acc[16][3] += kv * v4.w;
      }
      if (dg == 0) {
#pragma unroll
        for (int jm = 0; jm < 16; ++jm) kacc[jm] += ksh[i][mg + (jm << 4)];
        if (mg < 10) kacc[16] += ksh[i][mg + 256];
      }
    }
  }
  size_t sbase = ((size_t)bh * NCH + c) * (size_t)(NRFP * HD);
  size_t kbase = ((size_t)bh * NCH + c) * (size_t)NRF;
#pragma unroll
  for (int jm = 0; jm < 16; ++jm) {
    int m = mg + (jm << 4);
    short4 o = make_short4(f2bs(acc[jm][0]), f2bs(acc[jm][1]),
                           f2bs(acc[jm][2]), f2bs(acc[jm][3]));
    *(short4*)&Schunk[sbase + (size_t)m * HD + (dg << 2)] = o;
    if (dg == 0) ksum[kbase + m] = kacc[jm];
  }
  if (mg < 10) {
    int m = mg + 256;
    short4 o = make_short4(f2bs(acc[16][0]), f2bs(acc[16][1]),
                           f2bs(acc[16][2]), f2bs(acc[16][3]));
    *(short4*)&Schunk[sbase + (size_t)m * HD + (dg << 2)] = o;
    if (dg == 0) ksum[kbase + m] = kacc[16];
  }
  for (int idx = tid; idx < (NRFP - NRF) * HD; idx += 256) {
    int m = NRF + (idx >> 6), d = idx & 63;
    Schunk[sbase + (size_t)m * HD + d] = 0;
  }
}

// ---------------- exclusive prefix over chunks ----------------
__global__ __launch_bounds__(256) void prefix_S_bf(const short* __restrict__ Sc,
                                                   short* __restrict__ Sp) {
  int e = blockIdx.x * 256 + threadIdx.x;
  int bh = blockIdx.y;
  size_t base = (size_t)bh * NCH * (NRFP * HD) + e;
  float a = 0.f;
#pragma unroll
  for (int c = 0; c < NCH; ++c) {
    size_t idx = base + (size_t)c * (NRFP * HD);
    float v = bs2f(Sc[idx]);
    Sp[idx] = f2bs(a);
    a += v;
  }
}

__global__ void prefix_k_kernel(float* __restrict__ ksum) {
  int tid = blockIdx.x * 256 + threadIdx.x;
  if (tid >= NBH * NRF) return;
  int bh = tid / NRF;
  int m = tid - bh * NRF;
  size_t base = (size_t)bh * NCH * NRF + m;
  float a = 0.f;
#pragma unroll
  for (int c = 0; c < NCH; ++c) {
    size_t idx = base + (size_t)c * NRF;
    float v = ksum[idx];
    ksum[idx] = a;
    a += v;
  }
}

// ---------------- inter-chunk via MFMA ----------------
__global__ __launch_bounds__(256) void inter_mfma(
    const short* __restrict__ Qp, const short* __restrict__ Sp,
    const float* __restrict__ ksum, float* __restrict__ numA,
    float* __restrict__ denA) {
  int c = blockIdx.x, bh = blockIdx.y;
  __shared__ short Bs[64 * 296];
  __shared__ float ks[272];
  int tid = threadIdx.x, lane = tid & 63, wid = tid >> 6;
  const short* Spb = Sp + ((size_t)bh * NCH + c) * (size_t)(NRFP * HD);
  for (int idx = tid; idx < NRFP * HD; idx += 256) {
    int m = idx >> 6, d = idx & 63;
    Bs[d * 296 + m] = Spb[idx];
  }
  const float* ksb = ksum + ((size_t)bh * NCH + c) * (size_t)NRF;
  for (int idx = tid; idx < NRF; idx += 256) ks[idx] = ksb[idx];
  __syncthreads();
  int row0 = wid * 32;
  const short* Arow = Qp + ((size_t)bh * SEQ + (size_t)c * CHK + row0) * NRFP;
  f32x4 acc[2][4];
#pragma unroll
  for (int m = 0; m < 2; ++m)
#pragma unroll
    for (int n = 0; n < 4; ++n) acc[m][n] = f32x4{0.f, 0.f, 0.f, 0.f};
#pragma unroll
  for (int k9 = 0; k9 < 9; ++k9) {
    int kb = k9 * 32 + ((lane >> 4) << 3);
    bf16x8 af[2], bfv[4];
#pragma unroll
    for (int mf = 0; mf < 2; ++mf)
      af[mf] = *(const bf16x8*)(Arow + (size_t)(mf * 16 + (lane & 15)) * NRFP + kb);
#pragma unroll
    for (int nf = 0; nf < 4; ++nf)
      bfv[nf] = *(const bf16x8*)&Bs[(nf * 16 + (lane & 15)) * 296 + kb];
#pragma unroll
    for (int mf = 0; mf < 2; ++mf)
#pragma unroll
      for (int nf = 0; nf < 4; ++nf)
        acc[mf][nf] = __builtin_amdgcn_mfma_f32_16x16x32_bf16(af[mf], bfv[nf],
                                                              acc[mf][nf], 0, 0, 0);
  }
  size_t nb = ((size_t)bh * SEQ + (size_t)c * CHK + row0) * HD;
#pragma unroll
  for (int mf = 0; mf < 2; ++mf)
#pragma unroll
    for (int nf = 0; nf < 4; ++nf)
#pragma unroll
      for (int r = 0; r < 4; ++r) {
        int row = mf * 16 + ((lane >> 4) << 2) + r;
        int col = nf * 16 + (lane & 15);
        numA[nb + (size_t)row * HD + col] = acc[mf][nf][r];
      }
  int r = tid >> 1, half = tid & 1;
  const short* qr = Qp + ((size_t)bh * SEQ + (size_t)c * CHK + r) * NRFP;
  float s = 0.f;
  int m0 = half * 133;
  for (int m = m0; m < m0 + 133; ++m) s += bs2f(qr[m]) * ks[m];
  s += __shfl_xor(s, 1);
  if (!half) denA[(size_t)bh * SEQ + (size_t)c * CHK + r] = s;
}

// ---------------- intra-chunk via MFMA: P = mask(Q'K'^T); out = (numA + P@V)/(denA + rowsum P)
// grid (NCH, NBH), 256 threads = 4 waves; wave w owns rows w*32..w*32+31 of the 128-row chunk.
__global__ __launch_bounds__(256) void intra_mfma(
    const short* __restrict__ Qp, const short* __restrict__ Kp,
    const short* __restrict__ Vb, const float* __restrict__ numA,
    const float* __restrict__ denA, short* __restrict__ ctxb) {
  constexpr int PST = 136;  // LDS row stride (shorts): 272B -> 2-way-max conflicts on b128
  __shared__ short Pl[4 * 32 * PST];  // per-wave 32x128 P tile (bf16)
  __shared__ short Vt[64 * PST];      // V^T: [d][j]
  __shared__ float den_s[128];
  int c = blockIdx.x, bh = blockIdx.y;
  int b = bh >> 4, h = bh & 15;
  int tid = threadIdx.x, lane = tid & 63, wid = tid >> 6;
  int cl = lane & 15, rq = lane >> 4;
  size_t rowb = (size_t)bh * SEQ + (size_t)c * CHK;

  // stage V^T: Vt[d][j] = V[c*CHK+j][h*HD+d]
  {
    int jj = tid >> 3, d0 = (tid & 7) << 3;
#pragma unroll
    for (int jt = 0; jt < 4; ++jt) {
      int j = jj + jt * 32;
      bf16x8 v = *(const bf16x8*)(Vb + ((size_t)b * SEQ + (size_t)c * CHK + j) * DMODEL +
                                  h * HD + d0);
#pragma unroll
      for (int e = 0; e < 8; ++e) Vt[(d0 + e) * PST + j] = v[e];
    }
  }

  // ---- P phase: acc[mf][nf] covers rows i0+mf*16.., cols nf*16.. (within chunk) ----
  int i0 = wid * 32;
  const short* Arow = Qp + (rowb + i0) * NRFP;
  const short* Krow = Kp + rowb * NRFP;
  f32x4 acc[2][8];
#pragma unroll
  for (int m = 0; m < 2; ++m)
#pragma unroll
    for (int n = 0; n < 8; ++n) acc[m][n] = f32x4{0.f, 0.f, 0.f, 0.f};
#pragma unroll
  for (int k9 = 0; k9 < 9; ++k9) {
    int kb = k9 * 32 + (rq >> 1 ? 0 : 0) + ((lane >> 4) << 3);
    bf16x8 af[2];
#pragma unroll
    for (int mf = 0; mf < 2; ++mf)
      af[mf] = *(const bf16x8*)(Arow + (size_t)(mf * 16 + cl) * NRFP + kb);
#pragma unroll
    for (int nf = 0; nf < 8; ++nf) {
      bf16x8 bv = *(const bf16x8*)(Krow + (size_t)(nf * 16 + cl) * NRFP + kb);
#pragma unroll
      for (int mf = 0; mf < 2; ++mf)
        acc[mf][nf] = __builtin_amdgcn_mfma_f32_16x16x32_bf16(af[mf], bv,
                                                              acc[mf][nf], 0, 0, 0);
    }
  }
  // ---- mask, rowsum, write P to LDS ----
  float dsum[2][4];
#pragma unroll
  for (int mf = 0; mf < 2; ++mf)
#pragma unroll
    for (int r = 0; r < 4; ++r) dsum[mf][r] = 0.f;
#pragma unroll
  for (int mf = 0; mf < 2; ++mf)
#pragma unroll
    for (int r = 0; r < 4; ++r) {
      int rl = mf * 16 + (rq << 2) + r;  // row local to wave (0..31)
      int row = i0 + rl;                 // row within chunk
#pragma unroll
      for (int nf = 0; nf < 8; ++nf) {
        int col = nf * 16 + cl;
        float v = (col > row) ? 0.f : acc[mf][nf][r];
        dsum[mf][r] += v;
        Pl[wid * 32 * PST + rl * PST + col] = f2bs(v);
      }
    }
#pragma unroll
  for (int mf = 0; mf < 2; ++mf)
#pragma unroll
    for (int r = 0; r < 4; ++r) {
      float s = dsum[mf][r];
      s += __shfl_xor(s, 1);
      s += __shfl_xor(s, 2);
      s += __shfl_xor(s, 4);
      s += __shfl_xor(s, 8);
      if (cl == 0) den_s[i0 + mf * 16 + (rq << 2) + r] = s;
    }
  __syncthreads();

  // ---- PV phase: out[rl][d] over d=0..63, K-dim j=0..127 ----
  f32x4 pacc[2][4];
#pragma unroll
  for (int m = 0; m < 2; ++m)
#pragma unroll
    for (int n = 0; n < 4; ++n) pacc[m][n] = f32x4{0.f, 0.f, 0.f, 0.f};
#pragma unroll
  for (int kk = 0; kk < 4; ++kk) {
    int kb = kk * 32 + ((lane >> 4) << 3);
    bf16x8 paf[2];
#pragma unroll
    for (int mf = 0; mf < 2; ++mf)
      paf[mf] = *(const bf16x8*)&Pl[wid * 32 * PST + (mf * 16 + cl) * PST + kb];
#pragma unroll
    for (int nf = 0; nf < 4; ++nf) {
      bf16x8 bv = *(const bf16x8*)&Vt[(nf * 16 + cl) * PST + kb];
#pragma unroll
      for (int mf = 0; mf < 2; ++mf)
        pacc[mf][nf] = __builtin_amdgcn_mfma_f32_16x16x32_bf16(paf[mf], bv,
                                                               pacc[mf][nf], 0, 0, 0);
    }
  }
  // ---- finalize: (numA + PV) / (denA + den_intra) ----
#pragma unroll
  for (int mf = 0; mf < 2; ++mf)
#pragma unroll
    for (int r = 0; r < 4; ++r) {
      int row = i0 + mf * 16 + (rq << 2) + r;  // within chunk
      size_t grow = rowb + row;
      float inv = 1.0f / (denA[grow] + den_s[row]);
      size_t ob = ((size_t)b * SEQ + (size_t)c * CHK + row) * DMODEL + h * HD;
#pragma unroll
      for (int nf = 0; nf < 4; ++nf) {
        int d = nf * 16 + cl;
        float v = (numA[grow * HD + d] + pacc[mf][nf][r]) * inv;
        ctxb[ob + d] = f2bs(v);
      }
    }
}

// ---------------- launch ----------------
extern "C" void kernel_launch(void* const* d_in, const int* in_sizes, int n_in,
                              void* d_out, int out_size, void* d_ws, size_t ws_size,
                              hipStream_t stream) {
  (void)in_sizes; (void)n_in; (void)out_size;
  const float* query = (const float*)d_in[0];
  const float* key_  = (const float*)d_in[1];
  const float* value = (const float*)d_in[2];
  const float* Wq = (const float*)d_in[3];
  const float* bq = (const float*)d_in[4];
  const float* Wk = (const float*)d_in[5];
  const float* bk = (const float*)d_in[6];
  const float* Wv = (const float*)d_in[7];
  const float* bv = (const float*)d_in[8];
  const float* Wo = (const float*)d_in[9];
  const float* bo = (const float*)d_in[10];
  const float* rf = (const float*)d_in[11];

  constexpr size_t SZ_INBF = (size_t)NROWS * DMODEL * 2;
  constexpr size_t SZ_QP   = (size_t)NBH * SEQ * NRFP * 2;
  constexpr size_t SZ_WT   = (size_t)DMODEL * DMODEL * 2;
  constexpr size_t SZ_SCH  = (size_t)NBH * NCH * NRFP * HD * 2;
  constexpr size_t SZ_KS   = (size_t)NBH * NCH * NRF * 4;
  constexpr size_t SZ_HK   = (size_t)NBH * SEQ * 4;
  constexpr size_t SZ_NUMA = (size_t)NBH * SEQ * HD * 4;

  constexpr size_t O_QP   = 0;
  constexpr size_t O_KP   = O_QP + SZ_QP;
  constexpr size_t O_WT   = O_KP + SZ_QP;
  constexpr size_t O_QPR  = O_WT + 4 * SZ_WT;
  constexpr size_t O_KPR  = O_QPR + SZ_INBF;
  constexpr size_t O_VPR  = O_KPR + SZ_INBF;
  constexpr size_t O_SCH  = O_VPR + SZ_INBF;
  constexpr size_t O_SPR  = O_SCH + SZ_SCH;
  constexpr size_t O_KSUM = O_SPR + SZ_SCH;
  constexpr size_t O_HK   = O_KSUM + SZ_KS;
  constexpr size_t O_PMAX = O_HK + SZ_HK;
  constexpr size_t O_KST  = O_PMAX + (size_t)NROWS * 4;
  constexpr size_t O_NUMA = O_KST + 256;
  constexpr size_t O_DENA = O_NUMA + SZ_NUMA;
  constexpr size_t O_CTXB = O_DENA + SZ_HK;
  constexpr size_t O_END  = O_CTXB + SZ_INBF;
  if (ws_size < O_END) return;

  char* w = (char*)d_ws;
  short* Qbf = (short*)(w + O_QP);
  short* Kbf = (short*)(w + O_QP + SZ_INBF);
  short* Vbf = (short*)(w + O_QP + 2 * SZ_INBF);
  short* Qp  = (short*)(w + O_QP);
  short* Kp  = (short*)(w + O_KP);
  short* WtQ = (short*)(w + O_WT);
  short* WtK = (short*)(w + O_WT + SZ_WT);
  short* WtV = (short*)(w + O_WT + 2 * SZ_WT);
  short* WtO = (short*)(w + O_WT + 3 * SZ_WT);
  short* Qpr = (short*)(w + O_QPR);
  short* Kpr = (short*)(w + O_KPR);
  short* Vpr = (short*)(w + O_VPR);
  short* Sch = (short*)(w + O_SCH);
  short* Spr = (short*)(w + O_SPR);
  float* ksum = (float*)(w + O_KSUM);
  float* hkbuf = (float*)(w + O_HK);
  float* pmax = (float*)(w + O_PMAX);
  float* kstab = (float*)(w + O_KST);
  float* numA = (float*)(w + O_NUMA);
  float* denA = (float*)(w + O_DENA);
  short* ctxb = (short*)(w + O_CTXB);

  constexpr int NEL = NROWS * DMODEL;
  f32_to_bf16_k<<<NEL / (256 * 8), 256, 0, stream>>>(query, Qbf, NEL);
  f32_to_bf16_k<<<NEL / (256 * 8), 256, 0, stream>>>(key_, Kbf, NEL);
  f32_to_bf16_k<<<NEL / (256 * 8), 256, 0, stream>>>(value, Vbf, NEL);
  transpose_bf16<<<dim3(32, 32), 256, 0, stream>>>(Wq, WtQ);
  transpose_bf16<<<dim3(32, 32), 256, 0, stream>>>(Wk, WtK);
  transpose_bf16<<<dim3(32, 32), 256, 0, stream>>>(Wv, WtV);
  transpose_bf16<<<dim3(32, 32), 256, 0, stream>>>(Wo, WtO);
  gemm_bt<true><<<dim3(16, 32), 256, 0, stream>>>(Qbf, WtQ, bq, Qpr);
  gemm_bt<true><<<dim3(16, 32), 256, 0, stream>>>(Kbf, WtK, bk, Kpr);
  gemm_bt<true><<<dim3(16, 32), 256, 0, stream>>>(Vbf, WtV, bv, Vpr);
  hk_kernel<<<NROWS, 256, 0, stream>>>(Kpr, hkbuf, pmax);
  maxreduce_kernel<<<1, 256, 0, stream>>>(pmax, kstab);
  featmap_kernel<<<dim3(SEQ / 32, NBH, 2), 256, 0, stream>>>(Qpr, Kpr, rf, hkbuf,
                                                             kstab, Qp, Kp);
  chunksum_kernel<<<dim3(NCH, NBH), 256, 0, stream>>>(Kp, Vpr, Sch, ksum);
  prefix_S_bf<<<dim3(NRFP * HD / 256, NBH), 256, 0, stream>>>(Sch, Spr);
  prefix_k_kernel<<<(NBH * NRF + 255) / 256, 256, 0, stream>>>(ksum);
  inter_mfma<<<dim3(NCH, NBH), 256, 0, stream>>>(Qp, Spr, ksum, numA, denA);
  intra_mfma<<<dim3(NCH, NBH), 256, 0, stream>>>(Qp, Kp, Vpr, numA, denA, ctxb);
  gemm_bt<false><<<dim3(16, 32), 256, 0, stream>>>(ctxb, WtO, bo, d_out);
}

// Round 4
// 277.741 us; speedup vs baseline: 4.3400x; 1.3377x over previous
//
#include <hip/hip_runtime.h>
#include <hip/hip_bf16.h>

#define BATCH 2
#define SEQ 2048
#define DMODEL 1024
#define NH 16
#define HD 64
#define NRF 266
#define NRFP 288   // padded feature dim (multiple of 32), cols [266,288) are zero
#define CHK 128
#define NCH 16
#define NBH 32
#define NROWS 4096  // BATCH*SEQ

constexpr float SCAL = 0.17677669529663687f;   // DMODEL^-0.25
constexpr float SCAL2 = 0.03125f;              // SCAL^2 = DMODEL^-0.5
constexpr float CNORM = 0.06131393094576169f;  // 1/sqrt(NRF)
constexpr float KEPS = 1e-4f;

typedef short bf16x8 __attribute__((ext_vector_type(8)));
typedef float f32x4 __attribute__((ext_vector_type(4)));

__device__ __forceinline__ short f2bs(float v) {
  __hip_bfloat16 h = __float2bfloat16(v);
  return *reinterpret_cast<short*>(&h);
}
__device__ __forceinline__ float bs2f(short s) {
  __hip_bfloat16 h;
  *reinterpret_cast<short*>(&h) = s;
  return __bfloat162float(h);
}
__device__ __forceinline__ void gload_lds16(const void* g, void* l) {
  __builtin_amdgcn_global_load_lds(
      (const __attribute__((address_space(1))) void*)g,
      (__attribute__((address_space(3))) void*)l, 16, 0, 0);
}

// ---------------- f32 -> bf16 convert ----------------
__global__ __launch_bounds__(256) void f32_to_bf16_k(const float* __restrict__ x,
                                                     short* __restrict__ y, int n) {
  int i = (blockIdx.x * 256 + threadIdx.x) * 8;
  if (i >= n) return;
  float4 a = *(const float4*)&x[i];
  float4 b = *(const float4*)&x[i + 4];
  bf16x8 o;
  o[0] = f2bs(a.x); o[1] = f2bs(a.y); o[2] = f2bs(a.z); o[3] = f2bs(a.w);
  o[4] = f2bs(b.x); o[5] = f2bs(b.y); o[6] = f2bs(b.z); o[7] = f2bs(b.w);
  *(bf16x8*)&y[i] = o;
}

// ---------------- rf [266][64] f32 -> rfb [288][64] bf16, SCAL folded, padded ----------------
__global__ __launch_bounds__(256) void rf_pad_bf16(const float* __restrict__ rf,
                                                   short* __restrict__ rfb) {
  int idx = blockIdx.x * 256 + threadIdx.x;  // grid 72*256 = 18432 exact
  rfb[idx] = (idx < NRF * HD) ? f2bs(rf[idx] * SCAL) : (short)0;
}

// ---------------- W[K][N] f32 -> Wt[N][K] bf16 ----------------
__global__ __launch_bounds__(256) void transpose_bf16(const float* __restrict__ W,
                                                      short* __restrict__ Wt) {
  __shared__ float t[32][33];
  int k0 = blockIdx.y << 5, n0 = blockIdx.x << 5;
  int tx = threadIdx.x & 31, ty = threadIdx.x >> 5;  // ty 0..7
#pragma unroll
  for (int rr = 0; rr < 4; ++rr) {
    int r = ty + (rr << 3);
    t[r][tx] = W[(size_t)(k0 + r) * DMODEL + n0 + tx];
  }
  __syncthreads();
#pragma unroll
  for (int rr = 0; rr < 4; ++rr) {
    int r = ty + (rr << 3);
    Wt[(size_t)(n0 + r) * DMODEL + k0 + tx] = f2bs(t[tx][r]);
  }
}

// ---------------- MFMA GEMM: C[M x 1024] = A(bf16 [M][1024]) @ Bt(bf16 [1024][1024])^T + bias
template <bool OUTBF>
__global__ __launch_bounds__(256) void gemm_bt(const short* __restrict__ A,
                                               const short* __restrict__ Bt,
                                               const float* __restrict__ bias,
                                               void* __restrict__ C) {
  __shared__ short As[128 * 64];
  __shared__ short Bs[64 * 64];
  int tid = threadIdx.x;
  int bm = blockIdx.y << 7, bn = blockIdx.x << 6;
  int lane = tid & 63, wid = tid >> 6;
  int wr = wid >> 1, wc = wid & 1;
  f32x4 acc[4][2];
#pragma unroll
  for (int m = 0; m < 4; ++m)
#pragma unroll
    for (int n = 0; n < 2; ++n) acc[m][n] = f32x4{0.f, 0.f, 0.f, 0.f};

  for (int k0 = 0; k0 < DMODEL; k0 += 64) {
    __syncthreads();
#pragma unroll
    for (int i = 0; i < 4; ++i) {
      int e = tid * 8 + i * 2048;
      int row = e >> 6;
      int k = (e & 63) ^ ((row & 7) << 3);
      gload_lds16(A + (size_t)(bm + row) * DMODEL + k0 + k,
                  &As[(tid >> 6) * 512 + i * 2048]);
    }
#pragma unroll
    for (int i = 0; i < 2; ++i) {
      int e = tid * 8 + i * 2048;
      int row = e >> 6;
      int k = (e & 63) ^ ((row & 7) << 3);
      gload_lds16(Bt + (size_t)(bn + row) * DMODEL + k0 + k,
                  &Bs[(tid >> 6) * 512 + i * 2048]);
    }
    __syncthreads();
#pragma unroll
    for (int ks = 0; ks < 2; ++ks) {
      int kb = ks * 32 + ((lane >> 4) << 3);
      bf16x8 af[4], bfv[2];
#pragma unroll
      for (int mf = 0; mf < 4; ++mf) {
        int row = wr * 64 + mf * 16 + (lane & 15);
        af[mf] = *(const bf16x8*)&As[row * 64 + (kb ^ ((row & 7) << 3))];
      }
#pragma unroll
      for (int nf = 0; nf < 2; ++nf) {
        int row = wc * 32 + nf * 16 + (lane & 15);
        bfv[nf] = *(const bf16x8*)&Bs[row * 64 + (kb ^ ((row & 7) << 3))];
      }
#pragma unroll
      for (int mf = 0; mf < 4; ++mf)
#pragma unroll
        for (int nf = 0; nf < 2; ++nf)
          acc[mf][nf] = __builtin_amdgcn_mfma_f32_16x16x32_bf16(af[mf], bfv[nf],
                                                                acc[mf][nf], 0, 0, 0);
    }
  }
  int rbase = bm + wr * 64 + ((lane >> 4) << 2);
  int cbase = bn + wc * 32 + (lane & 15);
#pragma unroll
  for (int nf = 0; nf < 2; ++nf) {
    int col = cbase + nf * 16;
    float bv = bias[col];
#pragma unroll
    for (int mf = 0; mf < 4; ++mf)
#pragma unroll
      for (int r = 0; r < 4; ++r) {
        int row = rbase + mf * 16 + r;
        float v = acc[mf][nf][r] + bv;
        if (OUTBF)
          ((short*)C)[(size_t)row * DMODEL + col] = f2bs(v);
        else
          ((float*)C)[(size_t)row * DMODEL + col] = v;
      }
  }
}

// ---------------- h_k per (b,h,l) + per-block max (bf16 K input) ----------------
__global__ __launch_bounds__(256) void hk_kernel(const short* __restrict__ Kb,
                                                 float* __restrict__ hkbuf,
                                                 float* __restrict__ pmax) {
  int n = blockIdx.x;
  int tid = threadIdx.x;
  short4 kv = *(const short4*)(Kb + (size_t)n * DMODEL + tid * 4);
  float x0 = bs2f(kv.x), x1 = bs2f(kv.y), x2 = bs2f(kv.z), x3 = bs2f(kv.w);
  float ss = x0 * x0 + x1 * x1 + x2 * x2 + x3 * x3;
#pragma unroll
  for (int off = 8; off >= 1; off >>= 1) ss += __shfl_xor(ss, off, 16);
  float hkv = -0.5f * SCAL2 * ss;
  int h = tid >> 4;
  if ((tid & 15) == 0) {
    int b = n >> 11, l = n & (SEQ - 1);
    hkbuf[((size_t)(b * NH + h)) * SEQ + l] = hkv;
  }
  __shared__ float red[256];
  red[tid] = hkv;
  __syncthreads();
  for (int s = 128; s > 0; s >>= 1) {
    if (tid < s) red[tid] = fmaxf(red[tid], red[tid + s]);
    __syncthreads();
  }
  if (tid == 0) pmax[n] = red[0];
}

__global__ __launch_bounds__(256) void maxreduce_kernel(const float* __restrict__ pmax,
                                                        float* __restrict__ kstab) {
  int tid = threadIdx.x;
  float m = -3.0e38f;
  for (int i = tid; i < NROWS; i += 256) m = fmaxf(m, pmax[i]);
  __shared__ float red[256];
  red[tid] = m;
  __syncthreads();
  for (int s = 128; s > 0; s >>= 1) {
    if (tid < s) red[tid] = fmaxf(red[tid], red[tid + s]);
    __syncthreads();
  }
  if (tid == 0) *kstab = red[0];
}

// ---------------- feature map via MFMA ----------------
// grid (SEQ/128, NBH, 2); block 256 = 4 waves; wave owns 32 rows x 288 cols.
// A = X head-slice [128][64] (LDS, swizzled), B = rfb [288][64] (LDS, swizzled).
// Epilogue: exp(+hk-kstab for K), mask m>=266 -> 0, bounce via LDS for coalesced stores.
__global__ __launch_bounds__(256, 1) void featmap_mfma(
    const short* __restrict__ Qproj, const short* __restrict__ Kproj,
    const short* __restrict__ rfb, const float* __restrict__ hkbuf,
    const float* __restrict__ kstab, short* __restrict__ Qp, short* __restrict__ Kp) {
  __shared__ short smem[26624];  // A:8192 | B:18432 ; epilogue reuses as P[128][152]
  __shared__ float hks[128];
  short* As = smem;
  short* Bs = smem + 8192;
  int isK = blockIdx.z;
  const short* X = isK ? Kproj : Qproj;
  short* O = isK ? Kp : Qp;
  int bh = blockIdx.y, b = bh >> 4, h = bh & 15;
  int l0 = blockIdx.x << 7;
  int tid = threadIdx.x, lane = tid & 63, wid = tid >> 6;
  int cl = lane & 15, rq = lane >> 4;

  // stage A: 128 rows x 64 cols (head slice), XOR-swizzled source
#pragma unroll
  for (int i = 0; i < 4; ++i) {
    int e = tid * 8 + i * 2048;
    int row = e >> 6;
    int k = (e & 63) ^ ((row & 7) << 3);
    gload_lds16(X + ((size_t)b * SEQ + l0 + row) * DMODEL + h * HD + k,
                &As[wid * 512 + i * 2048]);
  }
  // stage B: rfb 288x64
#pragma unroll
  for (int i = 0; i < 9; ++i) {
    int e = tid * 8 + i * 2048;
    int row = e >> 6;
    int k = (e & 63) ^ ((row & 7) << 3);
    gload_lds16(rfb + row * HD + k, &Bs[wid * 512 + i * 2048]);
  }
  if (isK) {
    float ksv = *kstab;
    if (tid < 128) hks[tid] = hkbuf[(size_t)bh * SEQ + l0 + tid] - ksv;
  }
  __syncthreads();

  int i0 = wid * 32;
  f32x4 acc[2][18];
#pragma unroll
  for (int m = 0; m < 2; ++m)
#pragma unroll
    for (int n = 0; n < 18; ++n) acc[m][n] = f32x4{0.f, 0.f, 0.f, 0.f};
#pragma unroll
  for (int ks = 0; ks < 2; ++ks) {
    int kb = ks * 32 + (rq << 3);
    int swz = (cl & 7) << 3;
    bf16x8 af[2];
#pragma unroll
    for (int mf = 0; mf < 2; ++mf) {
      int row = i0 + mf * 16 + cl;
      af[mf] = *(const bf16x8*)&As[row * 64 + (kb ^ swz)];
    }
#pragma unroll
    for (int nf = 0; nf < 18; ++nf) {
      int brow = nf * 16 + cl;
      bf16x8 bv = *(const bf16x8*)&Bs[brow * 64 + (kb ^ swz)];
#pragma unroll
      for (int mf = 0; mf < 2; ++mf)
        acc[mf][nf] = __builtin_amdgcn_mfma_f32_16x16x32_bf16(af[mf], bv,
                                                              acc[mf][nf], 0, 0, 0);
    }
  }

  // epilogue: two 144-col halves through LDS for coalesced stores
  short* Ps = smem;  // [128][152]
#pragma unroll
  for (int hf = 0; hf < 2; ++hf) {
    __syncthreads();
#pragma unroll
    for (int mf = 0; mf < 2; ++mf)
#pragma unroll
      for (int r = 0; r < 4; ++r) {
        int rl = i0 + mf * 16 + (rq << 2) + r;
        float addk = isK ? hks[rl] : 0.f;
#pragma unroll
        for (int nf2 = 0; nf2 < 9; ++nf2) {
          int m = hf * 144 + nf2 * 16 + cl;
          float v = acc[mf][hf * 9 + nf2][r] + addk;
          float o = (m < NRF) ? CNORM * (expf(v) + KEPS) : 0.f;
          Ps[rl * 152 + nf2 * 16 + cl] = f2bs(o);
        }
      }
    __syncthreads();
#pragma unroll
    for (int it = 0; it < 9; ++it) {
      int idx = tid + it * 256;
      int row = idx / 18, ch = idx - row * 18;
      bf16x8 val = *(const bf16x8*)&Ps[row * 152 + ch * 8];
      *(bf16x8*)&O[((size_t)bh * SEQ + l0 + row) * NRFP + hf * 144 + ch * 8] = val;
    }
  }
}

// ---------------- per-chunk sums -> Schunk bf16 [bh][c][NRFP][64], ksum f32 ----------------
__global__ __launch_bounds__(256) void chunksum_kernel(
    const short* __restrict__ Kp, const short* __restrict__ Vb,
    short* __restrict__ Schunk, float* __restrict__ ksum) {
  int c = blockIdx.x, bh = blockIdx.y;
  int b = bh >> 4, h = bh & 15;
  __shared__ float ksh[32][NRF];
  __shared__ float vsh[32][HD];
  int tid = threadIdx.x;
  int mg = tid >> 4, dg = tid & 15;
  float acc[17][4];
#pragma unroll
  for (int jm = 0; jm < 17; ++jm)
#pragma unroll
    for (int jd = 0; jd < 4; ++jd) acc[jm][jd] = 0.f;
  float kacc[17];
#pragma unroll
  for (int jm = 0; jm < 17; ++jm) kacc[jm] = 0.f;
  for (int it = 0; it < 4; ++it) {
    __syncthreads();
    int i0 = c * CHK + (it << 5);
    for (int idx = tid; idx < 32 * NRF; idx += 256) {
      int i = idx / NRF, m = idx - i * NRF;
      ksh[i][m] = bs2f(Kp[((size_t)bh * SEQ + i0 + i) * NRFP + m]);
    }
    for (int idx = tid; idx < 32 * HD; idx += 256) {
      int i = idx >> 6, d = idx & 63;
      vsh[i][d] = bs2f(Vb[((size_t)b * SEQ + i0 + i) * DMODEL + h * HD + d]);
    }
    __syncthreads();
    for (int i = 0; i < 32; ++i) {
      float4 v4 = *(const float4*)&vsh[i][dg << 2];
#pragma unroll
      for (int jm = 0; jm < 16; ++jm) {
        float kv = ksh[i][mg + (jm << 4)];
        acc[jm][0] += kv * v4.x; acc[jm][1] += kv * v4.y;
        acc[jm][2] += kv * v4.z; acc[jm][3] += kv * v4.w;
      }
      if (mg < 10) {
        float kv = ksh[i][mg + 256];
        acc[16][0] += kv * v4.x; acc[16][1] += kv * v4.y;
        acc[16][2] += kv * v4.z; acc[16][3] += kv * v4.w;
      }
      if (dg == 0) {
#pragma unroll
        for (int jm = 0; jm < 16; ++jm) kacc[jm] += ksh[i][mg + (jm << 4)];
        if (mg < 10) kacc[16] += ksh[i][mg + 256];
      }
    }
  }
  size_t sbase = ((size_t)bh * NCH + c) * (size_t)(NRFP * HD);
  size_t kbase = ((size_t)bh * NCH + c) * (size_t)NRF;
#pragma unroll
  for (int jm = 0; jm < 16; ++jm) {
    int m = mg + (jm << 4);
    short4 o = make_short4(f2bs(acc[jm][0]), f2bs(acc[jm][1]),
                           f2bs(acc[jm][2]), f2bs(acc[jm][3]));
    *(short4*)&Schunk[sbase + (size_t)m * HD + (dg << 2)] = o;
    if (dg == 0) ksum[kbase + m] = kacc[jm];
  }
  if (mg < 10) {
    int m = mg + 256;
    short4 o = make_short4(f2bs(acc[16][0]), f2bs(acc[16][1]),
                           f2bs(acc[16][2]), f2bs(acc[16][3]));
    *(short4*)&Schunk[sbase + (size_t)m * HD + (dg << 2)] = o;
    if (dg == 0) ksum[kbase + m] = kacc[16];
  }
  for (int idx = tid; idx < (NRFP - NRF) * HD; idx += 256) {
    int m = NRF + (idx >> 6), d = idx & 63;
    Schunk[sbase + (size_t)m * HD + d] = 0;
  }
}

// ---------------- exclusive prefix over chunks ----------------
__global__ __launch_bounds__(256) void prefix_S_bf(const short* __restrict__ Sc,
                                                   short* __restrict__ Sp) {
  int e = blockIdx.x * 256 + threadIdx.x;
  int bh = blockIdx.y;
  size_t base = (size_t)bh * NCH * (NRFP * HD) + e;
  float a = 0.f;
#pragma unroll
  for (int c = 0; c < NCH; ++c) {
    size_t idx = base + (size_t)c * (NRFP * HD);
    float v = bs2f(Sc[idx]);
    Sp[idx] = f2bs(a);
    a += v;
  }
}

__global__ void prefix_k_kernel(float* __restrict__ ksum) {
  int tid = blockIdx.x * 256 + threadIdx.x;
  if (tid >= NBH * NRF) return;
  int bh = tid / NRF;
  int m = tid - bh * NRF;
  size_t base = (size_t)bh * NCH * NRF + m;
  float a = 0.f;
#pragma unroll
  for (int c = 0; c < NCH; ++c) {
    size_t idx = base + (size_t)c * NRF;
    float v = ksum[idx];
    ksum[idx] = a;
    a += v;
  }
}

// ---------------- inter-chunk via MFMA ----------------
__global__ __launch_bounds__(256) void inter_mfma(
    const short* __restrict__ Qp, const short* __restrict__ Sp,
    const float* __restrict__ ksum, float* __restrict__ numA,
    float* __restrict__ denA) {
  int c = blockIdx.x, bh = blockIdx.y;
  __shared__ short Bs[64 * 296];
  __shared__ float ks[272];
  int tid = threadIdx.x, lane = tid & 63, wid = tid >> 6;
  const short* Spb = Sp + ((size_t)bh * NCH + c) * (size_t)(NRFP * HD);
  for (int idx = tid; idx < NRFP * HD; idx += 256) {
    int m = idx >> 6, d = idx & 63;
    Bs[d * 296 + m] = Spb[idx];
  }
  const float* ksb = ksum + ((size_t)bh * NCH + c) * (size_t)NRF;
  for (int idx = tid; idx < NRF; idx += 256) ks[idx] = ksb[idx];
  __syncthreads();
  int row0 = wid * 32;
  const short* Arow = Qp + ((size_t)bh * SEQ + (size_t)c * CHK + row0) * NRFP;
  f32x4 acc[2][4];
#pragma unroll
  for (int m = 0; m < 2; ++m)
#pragma unroll
    for (int n = 0; n < 4; ++n) acc[m][n] = f32x4{0.f, 0.f, 0.f, 0.f};
#pragma unroll
  for (int k9 = 0; k9 < 9; ++k9) {
    int kb = k9 * 32 + ((lane >> 4) << 3);
    bf16x8 af[2], bfv[4];
#pragma unroll
    for (int mf = 0; mf < 2; ++mf)
      af[mf] = *(const bf16x8*)(Arow + (size_t)(mf * 16 + (lane & 15)) * NRFP + kb);
#pragma unroll
    for (int nf = 0; nf < 4; ++nf)
      bfv[nf] = *(const bf16x8*)&Bs[(nf * 16 + (lane & 15)) * 296 + kb];
#pragma unroll
    for (int mf = 0; mf < 2; ++mf)
#pragma unroll
      for (int nf = 0; nf < 4; ++nf)
        acc[mf][nf] = __builtin_amdgcn_mfma_f32_16x16x32_bf16(af[mf], bfv[nf],
                                                              acc[mf][nf], 0, 0, 0);
  }
  size_t nb = ((size_t)bh * SEQ + (size_t)c * CHK + row0) * HD;
#pragma unroll
  for (int mf = 0; mf < 2; ++mf)
#pragma unroll
    for (int nf = 0; nf < 4; ++nf)
#pragma unroll
      for (int r = 0; r < 4; ++r) {
        int row = mf * 16 + ((lane >> 4) << 2) + r;
        int col = nf * 16 + (lane & 15);
        numA[nb + (size_t)row * HD + col] = acc[mf][nf][r];
      }
  int r = tid >> 1, half = tid & 1;
  const short* qr = Qp + ((size_t)bh * SEQ + (size_t)c * CHK + r) * NRFP;
  float s = 0.f;
  int m0 = half * 133;
  for (int m = m0; m < m0 + 133; ++m) s += bs2f(qr[m]) * ks[m];
  s += __shfl_xor(s, 1);
  if (!half) denA[(size_t)bh * SEQ + (size_t)c * CHK + r] = s;
}

// ---------------- intra-chunk via MFMA ----------------
__global__ __launch_bounds__(256) void intra_mfma(
    const short* __restrict__ Qp, const short* __restrict__ Kp,
    const short* __restrict__ Vb, const float* __restrict__ numA,
    const float* __restrict__ denA, short* __restrict__ ctxb) {
  constexpr int PST = 136;
  __shared__ short Pl[4 * 32 * PST];
  __shared__ short Vt[64 * PST];
  __shared__ float den_s[128];
  int c = blockIdx.x, bh = blockIdx.y;
  int b = bh >> 4, h = bh & 15;
  int tid = threadIdx.x, lane = tid & 63, wid = tid >> 6;
  int cl = lane & 15, rq = lane >> 4;
  size_t rowb = (size_t)bh * SEQ + (size_t)c * CHK;

  {
    int jj = tid >> 3, d0 = (tid & 7) << 3;
#pragma unroll
    for (int jt = 0; jt < 4; ++jt) {
      int j = jj + jt * 32;
      bf16x8 v = *(const bf16x8*)(Vb + ((size_t)b * SEQ + (size_t)c * CHK + j) * DMODEL +
                                  h * HD + d0);
#pragma unroll
      for (int e = 0; e < 8; ++e) Vt[(d0 + e) * PST + j] = v[e];
    }
  }

  int i0 = wid * 32;
  const short* Arow = Qp + (rowb + i0) * NRFP;
  const short* Krow = Kp + rowb * NRFP;
  f32x4 acc[2][8];
#pragma unroll
  for (int m = 0; m < 2; ++m)
#pragma unroll
    for (int n = 0; n < 8; ++n) acc[m][n] = f32x4{0.f, 0.f, 0.f, 0.f};
#pragma unroll
  for (int k9 = 0; k9 < 9; ++k9) {
    int kb = k9 * 32 + ((lane >> 4) << 3);
    bf16x8 af[2];
#pragma unroll
    for (int mf = 0; mf < 2; ++mf)
      af[mf] = *(const bf16x8*)(Arow + (size_t)(mf * 16 + cl) * NRFP + kb);
#pragma unroll
    for (int nf = 0; nf < 8; ++nf) {
      bf16x8 bv = *(const bf16x8*)(Krow + (size_t)(nf * 16 + cl) * NRFP + kb);
#pragma unroll
      for (int mf = 0; mf < 2; ++mf)
        acc[mf][nf] = __builtin_amdgcn_mfma_f32_16x16x32_bf16(af[mf], bv,
                                                              acc[mf][nf], 0, 0, 0);
    }
  }
  float dsum[2][4];
#pragma unroll
  for (int mf = 0; mf < 2; ++mf)
#pragma unroll
    for (int r = 0; r < 4; ++r) dsum[mf][r] = 0.f;
#pragma unroll
  for (int mf = 0; mf < 2; ++mf)
#pragma unroll
    for (int r = 0; r < 4; ++r) {
      int rl = mf * 16 + (rq << 2) + r;
      int row = i0 + rl;
#pragma unroll
      for (int nf = 0; nf < 8; ++nf) {
        int col = nf * 16 + cl;
        float v = (col > row) ? 0.f : acc[mf][nf][r];
        dsum[mf][r] += v;
        Pl[wid * 32 * PST + rl * PST + col] = f2bs(v);
      }
    }
#pragma unroll
  for (int mf = 0; mf < 2; ++mf)
#pragma unroll
    for (int r = 0; r < 4; ++r) {
      float s = dsum[mf][r];
      s += __shfl_xor(s, 1);
      s += __shfl_xor(s, 2);
      s += __shfl_xor(s, 4);
      s += __shfl_xor(s, 8);
      if (cl == 0) den_s[i0 + mf * 16 + (rq << 2) + r] = s;
    }
  __syncthreads();

  f32x4 pacc[2][4];
#pragma unroll
  for (int m = 0; m < 2; ++m)
#pragma unroll
    for (int n = 0; n < 4; ++n) pacc[m][n] = f32x4{0.f, 0.f, 0.f, 0.f};
#pragma unroll
  for (int kk = 0; kk < 4; ++kk) {
    int kb = kk * 32 + ((lane >> 4) << 3);
    bf16x8 paf[2];
#pragma unroll
    for (int mf = 0; mf < 2; ++mf)
      paf[mf] = *(const bf16x8*)&Pl[wid * 32 * PST + (mf * 16 + cl) * PST + kb];
#pragma unroll
    for (int nf = 0; nf < 4; ++nf) {
      bf16x8 bv = *(const bf16x8*)&Vt[(nf * 16 + cl) * PST + kb];
#pragma unroll
      for (int mf = 0; mf < 2; ++mf)
        pacc[mf][nf] = __builtin_amdgcn_mfma_f32_16x16x32_bf16(paf[mf], bv,
                                                               pacc[mf][nf], 0, 0, 0);
    }
  }
#pragma unroll
  for (int mf = 0; mf < 2; ++mf)
#pragma unroll
    for (int r = 0; r < 4; ++r) {
      int row = i0 + mf * 16 + (rq << 2) + r;
      size_t grow = rowb + row;
      float inv = 1.0f / (denA[grow] + den_s[row]);
      size_t ob = ((size_t)b * SEQ + (size_t)c * CHK + row) * DMODEL + h * HD;
#pragma unroll
      for (int nf = 0; nf < 4; ++nf) {
        int d = nf * 16 + cl;
        float v = (numA[grow * HD + d] + pacc[mf][nf][r]) * inv;
        ctxb[ob + d] = f2bs(v);
      }
    }
}

// ---------------- launch ----------------
extern "C" void kernel_launch(void* const* d_in, const int* in_sizes, int n_in,
                              void* d_out, int out_size, void* d_ws, size_t ws_size,
                              hipStream_t stream) {
  (void)in_sizes; (void)n_in; (void)out_size;
  const float* query = (const float*)d_in[0];
  const float* key_  = (const float*)d_in[1];
  const float* value = (const float*)d_in[2];
  const float* Wq = (const float*)d_in[3];
  const float* bq = (const float*)d_in[4];
  const float* Wk = (const float*)d_in[5];
  const float* bk = (const float*)d_in[6];
  const float* Wv = (const float*)d_in[7];
  const float* bv = (const float*)d_in[8];
  const float* Wo = (const float*)d_in[9];
  const float* bo = (const float*)d_in[10];
  const float* rf = (const float*)d_in[11];

  constexpr size_t SZ_INBF = (size_t)NROWS * DMODEL * 2;
  constexpr size_t SZ_QP   = (size_t)NBH * SEQ * NRFP * 2;
  constexpr size_t SZ_WT   = (size_t)DMODEL * DMODEL * 2;
  constexpr size_t SZ_SCH  = (size_t)NBH * NCH * NRFP * HD * 2;
  constexpr size_t SZ_KS   = (size_t)NBH * NCH * NRF * 4;
  constexpr size_t SZ_HK   = (size_t)NBH * SEQ * 4;
  constexpr size_t SZ_NUMA = (size_t)NBH * SEQ * HD * 4;
  constexpr size_t SZ_RFB  = (size_t)NRFP * HD * 2;

  constexpr size_t O_QP   = 0;
  constexpr size_t O_KP   = O_QP + SZ_QP;
  constexpr size_t O_WT   = O_KP + SZ_QP;
  constexpr size_t O_QPR  = O_WT + 4 * SZ_WT;
  constexpr size_t O_KPR  = O_QPR + SZ_INBF;
  constexpr size_t O_VPR  = O_KPR + SZ_INBF;
  constexpr size_t O_SCH  = O_VPR + SZ_INBF;
  constexpr size_t O_SPR  = O_SCH + SZ_SCH;
  constexpr size_t O_KSUM = O_SPR + SZ_SCH;
  constexpr size_t O_HK   = O_KSUM + SZ_KS;
  constexpr size_t O_PMAX = O_HK + SZ_HK;
  constexpr size_t O_KST  = O_PMAX + (size_t)NROWS * 4;
  constexpr size_t O_NUMA = O_KST + 256;
  constexpr size_t O_DENA = O_NUMA + SZ_NUMA;
  constexpr size_t O_CTXB = O_DENA + SZ_HK;
  constexpr size_t O_RFB  = O_CTXB + SZ_INBF;
  constexpr size_t O_END  = O_RFB + SZ_RFB;
  if (ws_size < O_END) return;

  char* w = (char*)d_ws;
  short* Qbf = (short*)(w + O_QP);
  short* Kbf = (short*)(w + O_QP + SZ_INBF);
  short* Vbf = (short*)(w + O_QP + 2 * SZ_INBF);
  short* Qp  = (short*)(w + O_QP);
  short* Kp  = (short*)(w + O_KP);
  short* WtQ = (short*)(w + O_WT);
  short* WtK = (short*)(w + O_WT + SZ_WT);
  short* WtV = (short*)(w + O_WT + 2 * SZ_WT);
  short* WtO = (short*)(w + O_WT + 3 * SZ_WT);
  short* Qpr = (short*)(w + O_QPR);
  short* Kpr = (short*)(w + O_KPR);
  short* Vpr = (short*)(w + O_VPR);
  short* Sch = (short*)(w + O_SCH);
  short* Spr = (short*)(w + O_SPR);
  float* ksum = (float*)(w + O_KSUM);
  float* hkbuf = (float*)(w + O_HK);
  float* pmax = (float*)(w + O_PMAX);
  float* kstab = (float*)(w + O_KST);
  float* numA = (float*)(w + O_NUMA);
  float* denA = (float*)(w + O_DENA);
  short* ctxb = (short*)(w + O_CTXB);
  short* rfb  = (short*)(w + O_RFB);

  constexpr int NEL = NROWS * DMODEL;
  f32_to_bf16_k<<<NEL / (256 * 8), 256, 0, stream>>>(query, Qbf, NEL);
  f32_to_bf16_k<<<NEL / (256 * 8), 256, 0, stream>>>(key_, Kbf, NEL);
  f32_to_bf16_k<<<NEL / (256 * 8), 256, 0, stream>>>(value, Vbf, NEL);
  transpose_bf16<<<dim3(32, 32), 256, 0, stream>>>(Wq, WtQ);
  transpose_bf16<<<dim3(32, 32), 256, 0, stream>>>(Wk, WtK);
  transpose_bf16<<<dim3(32, 32), 256, 0, stream>>>(Wv, WtV);
  transpose_bf16<<<dim3(32, 32), 256, 0, stream>>>(Wo, WtO);
  rf_pad_bf16<<<(NRFP * HD) / 256, 256, 0, stream>>>(rf, rfb);
  gemm_bt<true><<<dim3(16, 32), 256, 0, stream>>>(Qbf, WtQ, bq, Qpr);
  gemm_bt<true><<<dim3(16, 32), 256, 0, stream>>>(Kbf, WtK, bk, Kpr);
  gemm_bt<true><<<dim3(16, 32), 256, 0, stream>>>(Vbf, WtV, bv, Vpr);
  hk_kernel<<<NROWS, 256, 0, stream>>>(Kpr, hkbuf, pmax);
  maxreduce_kernel<<<1, 256, 0, stream>>>(pmax, kstab);
  featmap_mfma<<<dim3(SEQ / 128, NBH, 2), 256, 0, stream>>>(Qpr, Kpr, rfb, hkbuf,
                                                            kstab, Qp, Kp);
  chunksum_kernel<<<dim3(NCH, NBH), 256, 0, stream>>>(Kp, Vpr, Sch, ksum);
  prefix_S_bf<<<dim3(NRFP * HD / 256, NBH), 256, 0, stream>>>(Sch, Spr);
  prefix_k_kernel<<<(NBH * NRF + 255) / 256, 256, 0, stream>>>(ksum);
  inter_mfma<<<dim3(NCH, NBH), 256, 0, stream>>>(Qp, Spr, ksum, numA, denA);
  intra_mfma<<<dim3(NCH, NBH), 256, 0, stream>>>(Qp, Kp, Vpr, numA, denA, ctxb);
  gemm_bt<false><<<dim3(16, 32), 256, 0, stream>>>(ctxb, WtO, bo, d_out);
}

// Round 5
// 232.164 us; speedup vs baseline: 5.1920x; 1.1963x over previous
//
#include <hip/hip_runtime.h>
#include <hip/hip_bf16.h>

#define BATCH 2
#define SEQ 2048
#define DMODEL 1024
#define NH 16
#define HD 64
#define NRF 266
#define NRFP 288   // padded feature dim (multiple of 32), cols [266,288) are zero
#define CHK 128
#define NCH 16
#define NBH 32
#define NROWS 4096  // BATCH*SEQ

constexpr float SCAL = 0.17677669529663687f;   // DMODEL^-0.25
constexpr float SCAL2 = 0.03125f;              // SCAL^2 = DMODEL^-0.5
constexpr float CNORM = 0.06131393094576169f;  // 1/sqrt(NRF)
constexpr float KEPS = 1e-4f;

typedef short bf16x8 __attribute__((ext_vector_type(8)));
typedef float f32x4 __attribute__((ext_vector_type(4)));

__device__ __forceinline__ short f2bs(float v) {
  __hip_bfloat16 h = __float2bfloat16(v);
  return *reinterpret_cast<short*>(&h);
}
__device__ __forceinline__ float bs2f(short s) {
  __hip_bfloat16 h;
  *reinterpret_cast<short*>(&h) = s;
  return __bfloat162float(h);
}
__device__ __forceinline__ void gload_lds16(const void* g, void* l) {
  __builtin_amdgcn_global_load_lds(
      (const __attribute__((address_space(1))) void*)g,
      (__attribute__((address_space(3))) void*)l, 16, 0, 0);
}

// ---------------- f32 -> bf16 convert ----------------
__global__ __launch_bounds__(256) void f32_to_bf16_k(const float* __restrict__ x,
                                                     short* __restrict__ y, int n) {
  int i = (blockIdx.x * 256 + threadIdx.x) * 8;
  if (i >= n) return;
  float4 a = *(const float4*)&x[i];
  float4 b = *(const float4*)&x[i + 4];
  bf16x8 o;
  o[0] = f2bs(a.x); o[1] = f2bs(a.y); o[2] = f2bs(a.z); o[3] = f2bs(a.w);
  o[4] = f2bs(b.x); o[5] = f2bs(b.y); o[6] = f2bs(b.z); o[7] = f2bs(b.w);
  *(bf16x8*)&y[i] = o;
}

// ---------------- rf [266][64] f32 -> rfb [288][64] bf16, SCAL folded, padded ----------------
__global__ __launch_bounds__(256) void rf_pad_bf16(const float* __restrict__ rf,
                                                   short* __restrict__ rfb) {
  int idx = blockIdx.x * 256 + threadIdx.x;  // grid 72*256 = 18432 exact
  rfb[idx] = (idx < NRF * HD) ? f2bs(rf[idx] * SCAL) : (short)0;
}

// ---------------- W[K][N] f32 -> Wt[N][K] bf16 ----------------
__global__ __launch_bounds__(256) void transpose_bf16(const float* __restrict__ W,
                                                      short* __restrict__ Wt) {
  __shared__ float t[32][33];
  int k0 = blockIdx.y << 5, n0 = blockIdx.x << 5;
  int tx = threadIdx.x & 31, ty = threadIdx.x >> 5;  // ty 0..7
#pragma unroll
  for (int rr = 0; rr < 4; ++rr) {
    int r = ty + (rr << 3);
    t[r][tx] = W[(size_t)(k0 + r) * DMODEL + n0 + tx];
  }
  __syncthreads();
#pragma unroll
  for (int rr = 0; rr < 4; ++rr) {
    int r = ty + (rr << 3);
    Wt[(size_t)(n0 + r) * DMODEL + k0 + tx] = f2bs(t[tx][r]);
  }
}

// ---------------- MFMA GEMM: C[M x 1024] = A(bf16 [M][1024]) @ Bt(bf16 [1024][1024])^T + bias
template <bool OUTBF>
__global__ __launch_bounds__(256) void gemm_bt(const short* __restrict__ A,
                                               const short* __restrict__ Bt,
                                               const float* __restrict__ bias,
                                               void* __restrict__ C) {
  __shared__ short As[128 * 64];
  __shared__ short Bs[64 * 64];
  int tid = threadIdx.x;
  int bm = blockIdx.y << 7, bn = blockIdx.x << 6;
  int lane = tid & 63, wid = tid >> 6;
  int wr = wid >> 1, wc = wid & 1;
  f32x4 acc[4][2];
#pragma unroll
  for (int m = 0; m < 4; ++m)
#pragma unroll
    for (int n = 0; n < 2; ++n) acc[m][n] = f32x4{0.f, 0.f, 0.f, 0.f};

  for (int k0 = 0; k0 < DMODEL; k0 += 64) {
    __syncthreads();
#pragma unroll
    for (int i = 0; i < 4; ++i) {
      int e = tid * 8 + i * 2048;
      int row = e >> 6;
      int k = (e & 63) ^ ((row & 7) << 3);
      gload_lds16(A + (size_t)(bm + row) * DMODEL + k0 + k,
                  &As[(tid >> 6) * 512 + i * 2048]);
    }
#pragma unroll
    for (int i = 0; i < 2; ++i) {
      int e = tid * 8 + i * 2048;
      int row = e >> 6;
      int k = (e & 63) ^ ((row & 7) << 3);
      gload_lds16(Bt + (size_t)(bn + row) * DMODEL + k0 + k,
                  &Bs[(tid >> 6) * 512 + i * 2048]);
    }
    __syncthreads();
#pragma unroll
    for (int ks = 0; ks < 2; ++ks) {
      int kb = ks * 32 + ((lane >> 4) << 3);
      bf16x8 af[4], bfv[2];
#pragma unroll
      for (int mf = 0; mf < 4; ++mf) {
        int row = wr * 64 + mf * 16 + (lane & 15);
        af[mf] = *(const bf16x8*)&As[row * 64 + (kb ^ ((row & 7) << 3))];
      }
#pragma unroll
      for (int nf = 0; nf < 2; ++nf) {
        int row = wc * 32 + nf * 16 + (lane & 15);
        bfv[nf] = *(const bf16x8*)&Bs[row * 64 + (kb ^ ((row & 7) << 3))];
      }
#pragma unroll
      for (int mf = 0; mf < 4; ++mf)
#pragma unroll
        for (int nf = 0; nf < 2; ++nf)
          acc[mf][nf] = __builtin_amdgcn_mfma_f32_16x16x32_bf16(af[mf], bfv[nf],
                                                                acc[mf][nf], 0, 0, 0);
    }
  }
  int rbase = bm + wr * 64 + ((lane >> 4) << 2);
  int cbase = bn + wc * 32 + (lane & 15);
#pragma unroll
  for (int nf = 0; nf < 2; ++nf) {
    int col = cbase + nf * 16;
    float bv = bias[col];
#pragma unroll
    for (int mf = 0; mf < 4; ++mf)
#pragma unroll
      for (int r = 0; r < 4; ++r) {
        int row = rbase + mf * 16 + r;
        float v = acc[mf][nf][r] + bv;
        if (OUTBF)
          ((short*)C)[(size_t)row * DMODEL + col] = f2bs(v);
        else
          ((float*)C)[(size_t)row * DMODEL + col] = v;
      }
  }
}

// ---------------- h_k per (b,h,l) + per-block max (bf16 K input) ----------------
__global__ __launch_bounds__(256) void hk_kernel(const short* __restrict__ Kb,
                                                 float* __restrict__ hkbuf,
                                                 float* __restrict__ pmax) {
  int n = blockIdx.x;
  int tid = threadIdx.x;
  short4 kv = *(const short4*)(Kb + (size_t)n * DMODEL + tid * 4);
  float x0 = bs2f(kv.x), x1 = bs2f(kv.y), x2 = bs2f(kv.z), x3 = bs2f(kv.w);
  float ss = x0 * x0 + x1 * x1 + x2 * x2 + x3 * x3;
#pragma unroll
  for (int off = 8; off >= 1; off >>= 1) ss += __shfl_xor(ss, off, 16);
  float hkv = -0.5f * SCAL2 * ss;
  int h = tid >> 4;
  if ((tid & 15) == 0) {
    int b = n >> 11, l = n & (SEQ - 1);
    hkbuf[((size_t)(b * NH + h)) * SEQ + l] = hkv;
  }
  __shared__ float red[256];
  red[tid] = hkv;
  __syncthreads();
  for (int s = 128; s > 0; s >>= 1) {
    if (tid < s) red[tid] = fmaxf(red[tid], red[tid + s]);
    __syncthreads();
  }
  if (tid == 0) pmax[n] = red[0];
}

__global__ __launch_bounds__(256) void maxreduce_kernel(const float* __restrict__ pmax,
                                                        float* __restrict__ kstab) {
  int tid = threadIdx.x;
  float m = -3.0e38f;
  for (int i = tid; i < NROWS; i += 256) m = fmaxf(m, pmax[i]);
  __shared__ float red[256];
  red[tid] = m;
  __syncthreads();
  for (int s = 128; s > 0; s >>= 1) {
    if (tid < s) red[tid] = fmaxf(red[tid], red[tid + s]);
    __syncthreads();
  }
  if (tid == 0) *kstab = red[0];
}

// ---------------- feature map via MFMA ----------------
__global__ __launch_bounds__(256, 1) void featmap_mfma(
    const short* __restrict__ Qproj, const short* __restrict__ Kproj,
    const short* __restrict__ rfb, const float* __restrict__ hkbuf,
    const float* __restrict__ kstab, short* __restrict__ Qp, short* __restrict__ Kp) {
  __shared__ short smem[26624];  // A:8192 | B:18432 ; epilogue reuses as P[128][152]
  __shared__ float hks[128];
  short* As = smem;
  short* Bs = smem + 8192;
  int isK = blockIdx.z;
  const short* X = isK ? Kproj : Qproj;
  short* O = isK ? Kp : Qp;
  int bh = blockIdx.y, b = bh >> 4, h = bh & 15;
  int l0 = blockIdx.x << 7;
  int tid = threadIdx.x, lane = tid & 63, wid = tid >> 6;
  int cl = lane & 15, rq = lane >> 4;

#pragma unroll
  for (int i = 0; i < 4; ++i) {
    int e = tid * 8 + i * 2048;
    int row = e >> 6;
    int k = (e & 63) ^ ((row & 7) << 3);
    gload_lds16(X + ((size_t)b * SEQ + l0 + row) * DMODEL + h * HD + k,
                &As[wid * 512 + i * 2048]);
  }
#pragma unroll
  for (int i = 0; i < 9; ++i) {
    int e = tid * 8 + i * 2048;
    int row = e >> 6;
    int k = (e & 63) ^ ((row & 7) << 3);
    gload_lds16(rfb + row * HD + k, &Bs[wid * 512 + i * 2048]);
  }
  if (isK) {
    float ksv = *kstab;
    if (tid < 128) hks[tid] = hkbuf[(size_t)bh * SEQ + l0 + tid] - ksv;
  }
  __syncthreads();

  int i0 = wid * 32;
  f32x4 acc[2][18];
#pragma unroll
  for (int m = 0; m < 2; ++m)
#pragma unroll
    for (int n = 0; n < 18; ++n) acc[m][n] = f32x4{0.f, 0.f, 0.f, 0.f};
#pragma unroll
  for (int ks = 0; ks < 2; ++ks) {
    int kb = ks * 32 + (rq << 3);
    int swz = (cl & 7) << 3;
    bf16x8 af[2];
#pragma unroll
    for (int mf = 0; mf < 2; ++mf) {
      int row = i0 + mf * 16 + cl;
      af[mf] = *(const bf16x8*)&As[row * 64 + (kb ^ swz)];
    }
#pragma unroll
    for (int nf = 0; nf < 18; ++nf) {
      int brow = nf * 16 + cl;
      bf16x8 bv = *(const bf16x8*)&Bs[brow * 64 + (kb ^ swz)];
#pragma unroll
      for (int mf = 0; mf < 2; ++mf)
        acc[mf][nf] = __builtin_amdgcn_mfma_f32_16x16x32_bf16(af[mf], bv,
                                                              acc[mf][nf], 0, 0, 0);
    }
  }

  short* Ps = smem;  // [128][152]
#pragma unroll
  for (int hf = 0; hf < 2; ++hf) {
    __syncthreads();
#pragma unroll
    for (int mf = 0; mf < 2; ++mf)
#pragma unroll
      for (int r = 0; r < 4; ++r) {
        int rl = i0 + mf * 16 + (rq << 2) + r;
        float addk = isK ? hks[rl] : 0.f;
#pragma unroll
        for (int nf2 = 0; nf2 < 9; ++nf2) {
          int m = hf * 144 + nf2 * 16 + cl;
          float v = acc[mf][hf * 9 + nf2][r] + addk;
          float o = (m < NRF) ? CNORM * (expf(v) + KEPS) : 0.f;
          Ps[rl * 152 + nf2 * 16 + cl] = f2bs(o);
        }
      }
    __syncthreads();
#pragma unroll
    for (int it = 0; it < 9; ++it) {
      int idx = tid + it * 256;
      int row = idx / 18, ch = idx - row * 18;
      bf16x8 val = *(const bf16x8*)&Ps[row * 152 + ch * 8];
      *(bf16x8*)&O[((size_t)bh * SEQ + l0 + row) * NRFP + hf * 144 + ch * 8] = val;
    }
  }
}

// ---------------- per-chunk sums via MFMA: Sc[m][d] = sum_i K'[i][m] V[i][d]
// grid (NCH, NBH), 256 thr = 4 waves. Stage K'^T [288][64-half] and V^T [64][64-half]
// in LDS (stride 70 to spread banks), contract i via 16x16x32 MFMA.
// Wave wv owns d-slice [wv*16, wv*16+16); acc = 18 m-frags.
__global__ __launch_bounds__(256) void chunksum_mfma(
    const short* __restrict__ Kp, const short* __restrict__ Vb,
    short* __restrict__ Schunk, float* __restrict__ ksum) {
  constexpr int ST = 70;
  __shared__ short KT[NRFP * ST];  // [m][i_loc]
  __shared__ short VT[HD * ST];    // [d][i_loc]
  int c = blockIdx.x, bh = blockIdx.y;
  int b = bh >> 4, h = bh & 15;
  int tid = threadIdx.x, lane = tid & 63, wv = tid >> 6;
  int cl = lane & 15, rq = lane >> 4;
  int irow = tid >> 2;  // 0..63
  int mq = tid & 3;
  size_t rowb = (size_t)bh * SEQ + (size_t)c * CHK;

  f32x4 acc[18];
#pragma unroll
  for (int m = 0; m < 18; ++m) acc[m] = f32x4{0.f, 0.f, 0.f, 0.f};
  float k1 = 0.f, k2 = 0.f;

  for (int hf = 0; hf < 2; ++hf) {
    __syncthreads();
    // stage K'^T: per-wave-inst writes are 64 consecutive i -> conflict-free
    const short* Krow = Kp + (rowb + hf * 64 + irow) * NRFP;
#pragma unroll
    for (int cg = 0; cg < 9; ++cg) {
      int m0 = cg * 32 + mq * 8;
      bf16x8 v = *(const bf16x8*)(Krow + m0);
#pragma unroll
      for (int e = 0; e < 8; ++e) KT[(m0 + e) * ST + irow] = v[e];
    }
    // stage V^T
    const short* Vrow =
        Vb + ((size_t)b * SEQ + (size_t)c * CHK + hf * 64 + irow) * DMODEL + h * HD;
    {
      int d0 = mq * 16;
      bf16x8 v0 = *(const bf16x8*)(Vrow + d0);
      bf16x8 v1 = *(const bf16x8*)(Vrow + d0 + 8);
#pragma unroll
      for (int e = 0; e < 8; ++e) VT[(d0 + e) * ST + irow] = v0[e];
#pragma unroll
      for (int e = 0; e < 8; ++e) VT[(d0 + 8 + e) * ST + irow] = v1[e];
    }
    __syncthreads();
    // MFMA over this half's 64 i (2 k-steps)
#pragma unroll
    for (int ks = 0; ks < 2; ++ks) {
      int kb = ks * 32 + rq * 8;
      bf16x8 bv = *(const bf16x8*)&VT[(wv * 16 + cl) * ST + kb];
#pragma unroll
      for (int mf = 0; mf < 18; ++mf) {
        bf16x8 av = *(const bf16x8*)&KT[(mf * 16 + cl) * ST + kb];
        acc[mf] = __builtin_amdgcn_mfma_f32_16x16x32_bf16(av, bv, acc[mf], 0, 0, 0);
      }
    }
    // ksum partials: thread sums KT row m=tid (and 256+tid for tid<10)
    {
      const short* r1 = &KT[tid * ST];
#pragma unroll
      for (int g = 0; g < 8; ++g) {
        bf16x8 v = *(const bf16x8*)(r1 + g * 8);
#pragma unroll
        for (int e = 0; e < 8; ++e) k1 += bs2f(v[e]);
      }
      if (tid < 10) {
        const short* r2 = &KT[(256 + tid) * ST];
#pragma unroll
        for (int g = 0; g < 8; ++g) {
          bf16x8 v = *(const bf16x8*)(r2 + g * 8);
#pragma unroll
          for (int e = 0; e < 8; ++e) k2 += bs2f(v[e]);
        }
      }
    }
  }
  // store S (bf16) and ksum (f32)
  size_t sbase = ((size_t)bh * NCH + c) * (size_t)(NRFP * HD);
  size_t kbase = ((size_t)bh * NCH + c) * (size_t)NRF;
#pragma unroll
  for (int mf = 0; mf < 18; ++mf)
#pragma unroll
    for (int r = 0; r < 4; ++r) {
      int m = mf * 16 + rq * 4 + r;
      Schunk[sbase + (size_t)m * HD + wv * 16 + cl] = f2bs(acc[mf][r]);
    }
  if (tid < NRF) ksum[kbase + tid] = k1;
  if (tid < 10) ksum[kbase + 256 + tid] = k2;
}

// ---------------- exclusive prefix over chunks ----------------
__global__ __launch_bounds__(256) void prefix_S_bf(const short* __restrict__ Sc,
                                                   short* __restrict__ Sp) {
  int e = blockIdx.x * 256 + threadIdx.x;
  int bh = blockIdx.y;
  size_t base = (size_t)bh * NCH * (NRFP * HD) + e;
  float a = 0.f;
#pragma unroll
  for (int c = 0; c < NCH; ++c) {
    size_t idx = base + (size_t)c * (NRFP * HD);
    float v = bs2f(Sc[idx]);
    Sp[idx] = f2bs(a);
    a += v;
  }
}

__global__ void prefix_k_kernel(float* __restrict__ ksum) {
  int tid = blockIdx.x * 256 + threadIdx.x;
  if (tid >= NBH * NRF) return;
  int bh = tid / NRF;
  int m = tid - bh * NRF;
  size_t base = (size_t)bh * NCH * NRF + m;
  float a = 0.f;
#pragma unroll
  for (int c = 0; c < NCH; ++c) {
    size_t idx = base + (size_t)c * NRF;
    float v = ksum[idx];
    ksum[idx] = a;
    a += v;
  }
}

// ---------------- inter-chunk via MFMA ----------------
__global__ __launch_bounds__(256) void inter_mfma(
    const short* __restrict__ Qp, const short* __restrict__ Sp,
    const float* __restrict__ ksum, float* __restrict__ numA,
    float* __restrict__ denA) {
  int c = blockIdx.x, bh = blockIdx.y;
  __shared__ short Bs[64 * 296];
  __shared__ float ks[272];
  int tid = threadIdx.x, lane = tid & 63, wid = tid >> 6;
  const short* Spb = Sp + ((size_t)bh * NCH + c) * (size_t)(NRFP * HD);
  for (int idx = tid; idx < NRFP * HD; idx += 256) {
    int m = idx >> 6, d = idx & 63;
    Bs[d * 296 + m] = Spb[idx];
  }
  const float* ksb = ksum + ((size_t)bh * NCH + c) * (size_t)NRF;
  for (int idx = tid; idx < NRF; idx += 256) ks[idx] = ksb[idx];
  __syncthreads();
  int row0 = wid * 32;
  const short* Arow = Qp + ((size_t)bh * SEQ + (size_t)c * CHK + row0) * NRFP;
  f32x4 acc[2][4];
#pragma unroll
  for (int m = 0; m < 2; ++m)
#pragma unroll
    for (int n = 0; n < 4; ++n) acc[m][n] = f32x4{0.f, 0.f, 0.f, 0.f};
#pragma unroll
  for (int k9 = 0; k9 < 9; ++k9) {
    int kb = k9 * 32 + ((lane >> 4) << 3);
    bf16x8 af[2], bfv[4];
#pragma unroll
    for (int mf = 0; mf < 2; ++mf)
      af[mf] = *(const bf16x8*)(Arow + (size_t)(mf * 16 + (lane & 15)) * NRFP + kb);
#pragma unroll
    for (int nf = 0; nf < 4; ++nf)
      bfv[nf] = *(const bf16x8*)&Bs[(nf * 16 + (lane & 15)) * 296 + kb];
#pragma unroll
    for (int mf = 0; mf < 2; ++mf)
#pragma unroll
      for (int nf = 0; nf < 4; ++nf)
        acc[mf][nf] = __builtin_amdgcn_mfma_f32_16x16x32_bf16(af[mf], bfv[nf],
                                                              acc[mf][nf], 0, 0, 0);
  }
  size_t nb = ((size_t)bh * SEQ + (size_t)c * CHK + row0) * HD;
#pragma unroll
  for (int mf = 0; mf < 2; ++mf)
#pragma unroll
    for (int nf = 0; nf < 4; ++nf)
#pragma unroll
      for (int r = 0; r < 4; ++r) {
        int row = mf * 16 + ((lane >> 4) << 2) + r;
        int col = nf * 16 + (lane & 15);
        numA[nb + (size_t)row * HD + col] = acc[mf][nf][r];
      }
  int r = tid >> 1, half = tid & 1;
  const short* qr = Qp + ((size_t)bh * SEQ + (size_t)c * CHK + r) * NRFP;
  float s = 0.f;
  int m0 = half * 133;
  for (int m = m0; m < m0 + 133; ++m) s += bs2f(qr[m]) * ks[m];
  s += __shfl_xor(s, 1);
  if (!half) denA[(size_t)bh * SEQ + (size_t)c * CHK + r] = s;
}

// ---------------- intra-chunk via MFMA ----------------
__global__ __launch_bounds__(256) void intra_mfma(
    const short* __restrict__ Qp, const short* __restrict__ Kp,
    const short* __restrict__ Vb, const float* __restrict__ numA,
    const float* __restrict__ denA, short* __restrict__ ctxb) {
  constexpr int PST = 136;
  __shared__ short Pl[4 * 32 * PST];
  __shared__ short Vt[64 * PST];
  __shared__ float den_s[128];
  int c = blockIdx.x, bh = blockIdx.y;
  int b = bh >> 4, h = bh & 15;
  int tid = threadIdx.x, lane = tid & 63, wid = tid >> 6;
  int cl = lane & 15, rq = lane >> 4;
  size_t rowb = (size_t)bh * SEQ + (size_t)c * CHK;

  {
    int jj = tid >> 3, d0 = (tid & 7) << 3;
#pragma unroll
    for (int jt = 0; jt < 4; ++jt) {
      int j = jj + jt * 32;
      bf16x8 v = *(const bf16x8*)(Vb + ((size_t)b * SEQ + (size_t)c * CHK + j) * DMODEL +
                                  h * HD + d0);
#pragma unroll
      for (int e = 0; e < 8; ++e) Vt[(d0 + e) * PST + j] = v[e];
    }
  }

  int i0 = wid * 32;
  const short* Arow = Qp + (rowb + i0) * NRFP;
  const short* Krow = Kp + rowb * NRFP;
  f32x4 acc[2][8];
#pragma unroll
  for (int m = 0; m < 2; ++m)
#pragma unroll
    for (int n = 0; n < 8; ++n) acc[m][n] = f32x4{0.f, 0.f, 0.f, 0.f};
#pragma unroll
  for (int k9 = 0; k9 < 9; ++k9) {
    int kb = k9 * 32 + ((lane >> 4) << 3);
    bf16x8 af[2];
#pragma unroll
    for (int mf = 0; mf < 2; ++mf)
      af[mf] = *(const bf16x8*)(Arow + (size_t)(mf * 16 + cl) * NRFP + kb);
#pragma unroll
    for (int nf = 0; nf < 8; ++nf) {
      bf16x8 bv = *(const bf16x8*)(Krow + (size_t)(nf * 16 + cl) * NRFP + kb);
#pragma unroll
      for (int mf = 0; mf < 2; ++mf)
        acc[mf][nf] = __builtin_amdgcn_mfma_f32_16x16x32_bf16(af[mf], bv,
                                                              acc[mf][nf], 0, 0, 0);
    }
  }
  float dsum[2][4];
#pragma unroll
  for (int mf = 0; mf < 2; ++mf)
#pragma unroll
    for (int r = 0; r < 4; ++r) dsum[mf][r] = 0.f;
#pragma unroll
  for (int mf = 0; mf < 2; ++mf)
#pragma unroll
    for (int r = 0; r < 4; ++r) {
      int rl = mf * 16 + (rq << 2) + r;
      int row = i0 + rl;
#pragma unroll
      for (int nf = 0; nf < 8; ++nf) {
        int col = nf * 16 + cl;
        float v = (col > row) ? 0.f : acc[mf][nf][r];
        dsum[mf][r] += v;
        Pl[wid * 32 * PST + rl * PST + col] = f2bs(v);
      }
    }
#pragma unroll
  for (int mf = 0; mf < 2; ++mf)
#pragma unroll
    for (int r = 0; r < 4; ++r) {
      float s = dsum[mf][r];
      s += __shfl_xor(s, 1);
      s += __shfl_xor(s, 2);
      s += __shfl_xor(s, 4);
      s += __shfl_xor(s, 8);
      if (cl == 0) den_s[i0 + mf * 16 + (rq << 2) + r] = s;
    }
  __syncthreads();

  f32x4 pacc[2][4];
#pragma unroll
  for (int m = 0; m < 2; ++m)
#pragma unroll
    for (int n = 0; n < 4; ++n) pacc[m][n] = f32x4{0.f, 0.f, 0.f, 0.f};
#pragma unroll
  for (int kk = 0; kk < 4; ++kk) {
    int kb = kk * 32 + ((lane >> 4) << 3);
    bf16x8 paf[2];
#pragma unroll
    for (int mf = 0; mf < 2; ++mf)
      paf[mf] = *(const bf16x8*)&Pl[wid * 32 * PST + (mf * 16 + cl) * PST + kb];
#pragma unroll
    for (int nf = 0; nf < 4; ++nf) {
      bf16x8 bv = *(const bf16x8*)&Vt[(nf * 16 + cl) * PST + kb];
#pragma unroll
      for (int mf = 0; mf < 2; ++mf)
        pacc[mf][nf] = __builtin_amdgcn_mfma_f32_16x16x32_bf16(paf[mf], bv,
                                                               pacc[mf][nf], 0, 0, 0);
    }
  }
#pragma unroll
  for (int mf = 0; mf < 2; ++mf)
#pragma unroll
    for (int r = 0; r < 4; ++r) {
      int row = i0 + mf * 16 + (rq << 2) + r;
      size_t grow = rowb + row;
      float inv = 1.0f / (denA[grow] + den_s[row]);
      size_t ob = ((size_t)b * SEQ + (size_t)c * CHK + row) * DMODEL + h * HD;
#pragma unroll
      for (int nf = 0; nf < 4; ++nf) {
        int d = nf * 16 + cl;
        float v = (numA[grow * HD + d] + pacc[mf][nf][r]) * inv;
        ctxb[ob + d] = f2bs(v);
      }
    }
}

// ---------------- launch ----------------
extern "C" void kernel_launch(void* const* d_in, const int* in_sizes, int n_in,
                              void* d_out, int out_size, void* d_ws, size_t ws_size,
                              hipStream_t stream) {
  (void)in_sizes; (void)n_in; (void)out_size;
  const float* query = (const float*)d_in[0];
  const float* key_  = (const float*)d_in[1];
  const float* value = (const float*)d_in[2];
  const float* Wq = (const float*)d_in[3];
  const float* bq = (const float*)d_in[4];
  const float* Wk = (const float*)d_in[5];
  const float* bk = (const float*)d_in[6];
  const float* Wv = (const float*)d_in[7];
  const float* bv = (const float*)d_in[8];
  const float* Wo = (const float*)d_in[9];
  const float* bo = (const float*)d_in[10];
  const float* rf = (const float*)d_in[11];

  constexpr size_t SZ_INBF = (size_t)NROWS * DMODEL * 2;
  constexpr size_t SZ_QP   = (size_t)NBH * SEQ * NRFP * 2;
  constexpr size_t SZ_WT   = (size_t)DMODEL * DMODEL * 2;
  constexpr size_t SZ_SCH  = (size_t)NBH * NCH * NRFP * HD * 2;
  constexpr size_t SZ_KS   = (size_t)NBH * NCH * NRF * 4;
  constexpr size_t SZ_HK   = (size_t)NBH * SEQ * 4;
  constexpr size_t SZ_NUMA = (size_t)NBH * SEQ * HD * 4;
  constexpr size_t SZ_RFB  = (size_t)NRFP * HD * 2;

  constexpr size_t O_QP   = 0;
  constexpr size_t O_KP   = O_QP + SZ_QP;
  constexpr size_t O_WT   = O_KP + SZ_QP;
  constexpr size_t O_QPR  = O_WT + 4 * SZ_WT;
  constexpr size_t O_KPR  = O_QPR + SZ_INBF;
  constexpr size_t O_VPR  = O_KPR + SZ_INBF;
  constexpr size_t O_SCH  = O_VPR + SZ_INBF;
  constexpr size_t O_SPR  = O_SCH + SZ_SCH;
  constexpr size_t O_KSUM = O_SPR + SZ_SCH;
  constexpr size_t O_HK   = O_KSUM + SZ_KS;
  constexpr size_t O_PMAX = O_HK + SZ_HK;
  constexpr size_t O_KST  = O_PMAX + (size_t)NROWS * 4;
  constexpr size_t O_NUMA = O_KST + 256;
  constexpr size_t O_DENA = O_NUMA + SZ_NUMA;
  constexpr size_t O_CTXB = O_DENA + SZ_HK;
  constexpr size_t O_RFB  = O_CTXB + SZ_INBF;
  constexpr size_t O_END  = O_RFB + SZ_RFB;
  if (ws_size < O_END) return;

  char* w = (char*)d_ws;
  short* Qbf = (short*)(w + O_QP);
  short* Kbf = (short*)(w + O_QP + SZ_INBF);
  short* Vbf = (short*)(w + O_QP + 2 * SZ_INBF);
  short* Qp  = (short*)(w + O_QP);
  short* Kp  = (short*)(w + O_KP);
  short* WtQ = (short*)(w + O_WT);
  short* WtK = (short*)(w + O_WT + SZ_WT);
  short* WtV = (short*)(w + O_WT + 2 * SZ_WT);
  short* WtO = (short*)(w + O_WT + 3 * SZ_WT);
  short* Qpr = (short*)(w + O_QPR);
  short* Kpr = (short*)(w + O_KPR);
  short* Vpr = (short*)(w + O_VPR);
  short* Sch = (short*)(w + O_SCH);
  short* Spr = (short*)(w + O_SPR);
  float* ksum = (float*)(w + O_KSUM);
  float* hkbuf = (float*)(w + O_HK);
  float* pmax = (float*)(w + O_PMAX);
  float* kstab = (float*)(w + O_KST);
  float* numA = (float*)(w + O_NUMA);
  float* denA = (float*)(w + O_DENA);
  short* ctxb = (short*)(w + O_CTXB);
  short* rfb  = (short*)(w + O_RFB);

  constexpr int NEL = NROWS * DMODEL;
  f32_to_bf16_k<<<NEL / (256 * 8), 256, 0, stream>>>(query, Qbf, NEL);
  f32_to_bf16_k<<<NEL / (256 * 8), 256, 0, stream>>>(key_, Kbf, NEL);
  f32_to_bf16_k<<<NEL / (256 * 8), 256, 0, stream>>>(value, Vbf, NEL);
  transpose_bf16<<<dim3(32, 32), 256, 0, stream>>>(Wq, WtQ);
  transpose_bf16<<<dim3(32, 32), 256, 0, stream>>>(Wk, WtK);
  transpose_bf16<<<dim3(32, 32), 256, 0, stream>>>(Wv, WtV);
  transpose_bf16<<<dim3(32, 32), 256, 0, stream>>>(Wo, WtO);
  rf_pad_bf16<<<(NRFP * HD) / 256, 256, 0, stream>>>(rf, rfb);
  gemm_bt<true><<<dim3(16, 32), 256, 0, stream>>>(Qbf, WtQ, bq, Qpr);
  gemm_bt<true><<<dim3(16, 32), 256, 0, stream>>>(Kbf, WtK, bk, Kpr);
  gemm_bt<true><<<dim3(16, 32), 256, 0, stream>>>(Vbf, WtV, bv, Vpr);
  hk_kernel<<<NROWS, 256, 0, stream>>>(Kpr, hkbuf, pmax);
  maxreduce_kernel<<<1, 256, 0, stream>>>(pmax, kstab);
  featmap_mfma<<<dim3(SEQ / 128, NBH, 2), 256, 0, stream>>>(Qpr, Kpr, rfb, hkbuf,
                                                            kstab, Qp, Kp);
  chunksum_mfma<<<dim3(NCH, NBH), 256, 0, stream>>>(Kp, Vpr, Sch, ksum);
  prefix_S_bf<<<dim3(NRFP * HD / 256, NBH), 256, 0, stream>>>(Sch, Spr);
  prefix_k_kernel<<<(NBH * NRF + 255) / 256, 256, 0, stream>>>(ksum);
  inter_mfma<<<dim3(NCH, NBH), 256, 0, stream>>>(Qp, Spr, ksum, numA, denA);
  intra_mfma<<<dim3(NCH, NBH), 256, 0, stream>>>(Qp, Kp, Vpr, numA, denA, ctxb);
  gemm_bt<false><<<dim3(16, 32), 256, 0, stream>>>(ctxb, WtO, bo, d_out);
}